// Round 3
// baseline (310.761 us; speedup 1.0000x reference)
//
#include <hip/hip_runtime.h>

#define NB   4
#define C_IN 256
#define CQD  64
#define NPT  4096
#define L2E  1.44269504088896f

typedef __attribute__((ext_vector_type(8))) short bf16x8;
typedef __attribute__((ext_vector_type(4))) float f32x4;
typedef unsigned short u16;
typedef unsigned int   u32;

#define EXP2F(x)      __builtin_amdgcn_exp2f(x)
#define MFMA32(A,B,C) __builtin_amdgcn_mfma_f32_16x16x32_bf16(A,B,C,0,0,0)

__device__ __forceinline__ u16 f2bf(float f) {          // RNE (cold paths)
    u32 u = __float_as_uint(f);
    u += 0x7fff + ((u >> 16) & 1);
    return (u16)(u >> 16);
}
// one v_perm: (bf16_trunc(hi)<<16) | bf16_trunc(lo)
__device__ __forceinline__ u32 pack_trunc(float lo, float hi) {
    return __builtin_amdgcn_perm(__float_as_uint(hi), __float_as_uint(lo), 0x07060302u);
}

// ---------------------------------------------------------------------------
// prep: pack wq|wk|wv into bf16 wbf[384][256], biases into bias[384]
// ---------------------------------------------------------------------------
__global__ void prep_kernel(
    const float* __restrict__ wq, const float* __restrict__ bq,
    const float* __restrict__ wk, const float* __restrict__ bk,
    const float* __restrict__ wv, const float* __restrict__ bv,
    u16* __restrict__ wbf, float* __restrict__ bias)
{
    const int gid = blockIdx.x*256 + threadIdx.x;
    if (gid < 384*256) {
        const int r = gid >> 8, c = gid & 255;
        const float v = (r < 64) ? wq[r*256 + c]
                      : (r < 128) ? wk[(r-64)*256 + c]
                                  : wv[(r-128)*256 + c];
        wbf[gid] = f2bf(v);
    } else if (gid < 384*256 + 384) {
        const int r = gid - 384*256;
        bias[r] = (r < 64) ? bq[r] : (r < 128) ? bk[r-64] : bv[r-128];
    }
}

// ---------------------------------------------------------------------------
// proj: MFMA pointwise projections, x read ONCE. Wave w owns tiles T=4*ot+w.
// grid (N/32, B), block 256.
// ---------------------------------------------------------------------------
union ProjShared {
    u16 x_t[32][264];                            // [n][c] bf16, stride 528B
    struct { u16 qk[32][136]; u16 vl[256][40]; } ep;
};

__global__ __launch_bounds__(256) void proj_kernel(
    const float* __restrict__ x, const u16* __restrict__ wbf,
    const float* __restrict__ bias,
    u16* __restrict__ qT, u16* __restrict__ kT, u16* __restrict__ vbf)
{
    __shared__ ProjShared sh;

    const int t  = threadIdx.x;
    const int n0 = blockIdx.x * 32;
    const int b  = blockIdx.y;

    {   // stage x tile transposed -> bf16 LDS
        const int ln = t & 31;
        const int cg = t >> 5;
        #pragma unroll
        for (int rr = 0; rr < 8; rr++) {
            const int c = 4*cg + 32*rr;
            const float f0 = x[((size_t)(b*C_IN + c+0))*NPT + n0 + ln];
            const float f1 = x[((size_t)(b*C_IN + c+1))*NPT + n0 + ln];
            const float f2 = x[((size_t)(b*C_IN + c+2))*NPT + n0 + ln];
            const float f3 = x[((size_t)(b*C_IN + c+3))*NPT + n0 + ln];
            ushort4 u4;
            u4.x = f2bf(f0); u4.y = f2bf(f1); u4.z = f2bf(f2); u4.w = f2bf(f3);
            *(ushort4*)&sh.x_t[ln][c] = u4;
        }
    }
    __syncthreads();

    const int w = t >> 6, l = t & 63, q = l >> 4, c16 = l & 15;

    f32x4 acc[6][2];
    #pragma unroll
    for (int ot = 0; ot < 6; ot++)
        #pragma unroll
        for (int nt = 0; nt < 2; nt++)
            acc[ot][nt] = (f32x4){0.f, 0.f, 0.f, 0.f};

    #pragma unroll
    for (int kk = 0; kk < 8; kk++) {
        const bf16x8 bf0 = *(const bf16x8*)&sh.x_t[c16     ][kk*32 + 8*q];
        const bf16x8 bf1 = *(const bf16x8*)&sh.x_t[16 + c16][kk*32 + 8*q];
        #pragma unroll
        for (int ot = 0; ot < 6; ot++) {
            const int o = 16*(4*ot + w) + c16;
            const bf16x8 af = *(const bf16x8*)&wbf[(size_t)o*C_IN + kk*32 + 8*q];
            acc[ot][0] = MFMA32(af, bf0, acc[ot][0]);
            acc[ot][1] = MFMA32(af, bf1, acc[ot][1]);
        }
    }
    __syncthreads();   // x_t dead; reuse LDS for epilogue staging

    #pragma unroll
    for (int ot = 0; ot < 6; ot++) {
        const int T  = 4*ot + w;
        const int ob = 16*T + 4*q;
        float b0 = bias[ob+0], b1 = bias[ob+1], b2 = bias[ob+2], b3 = bias[ob+3];
        #pragma unroll
        for (int nt = 0; nt < 2; nt++) {
            const f32x4 a = acc[ot][nt];
            const float v0 = a[0]+b0, v1 = a[1]+b1, v2 = a[2]+b2, v3 = a[3]+b3;
            if (ot < 2) {
                uint2 u;
                u.x = (u32)f2bf(v0) | ((u32)f2bf(v1) << 16);
                u.y = (u32)f2bf(v2) | ((u32)f2bf(v3) << 16);
                *(uint2*)&sh.ep.qk[16*nt + c16][16*T + 4*q] = u;
            } else {
                const int cb = 16*T - 128 + 4*q;
                sh.ep.vl[cb+0][16*nt + c16] = f2bf(v0);
                sh.ep.vl[cb+1][16*nt + c16] = f2bf(v1);
                sh.ep.vl[cb+2][16*nt + c16] = f2bf(v2);
                sh.ep.vl[cb+3][16*nt + c16] = f2bf(v3);
            }
        }
    }
    __syncthreads();

    {   // coalesced global stores
        const int n  = t >> 3;
        const int o8 = (t & 7) * 8;
        *(uint4*)&qT[((size_t)b*NPT + n0 + n)*CQD + o8] = *(uint4*)&sh.ep.qk[n][o8];
        *(uint4*)&kT[((size_t)b*NPT + n0 + n)*CQD + o8] = *(uint4*)&sh.ep.qk[n][64 + o8];
        u16* vrow = &vbf[((size_t)b*C_IN + t)*NPT + n0];
        #pragma unroll
        for (int j = 0; j < 4; j++)
            *(uint4*)&vrow[8*j] = *(uint4*)&sh.ep.vl[t][8*j];
    }
}

// ---------------------------------------------------------------------------
// stats: no-max partial softmax sums over 1024-wide m-split via MFMA.
// grid (4 msplit, N/64, B), block 256.
// ---------------------------------------------------------------------------
__global__ __launch_bounds__(256) void stats_kernel(
    const u16* __restrict__ qT, const u16* __restrict__ kT,
    float* __restrict__ psum)
{
    const int t = threadIdx.x;
    const int w = t >> 6, l = t & 63, q = l >> 4, c16 = l & 15;
    const int ms = blockIdx.x, nt = blockIdx.y, b = blockIdx.z;
    const int nb = nt*64 + 16*w;

    const bf16x8* qp = (const bf16x8*)&qT[((size_t)b*NPT + nb + c16)*CQD + 8*q];
    const bf16x8 aq0 = qp[0];
    const bf16x8 aq1 = qp[4];

    float rz[4] = {0.f, 0.f, 0.f, 0.f};

    for (int m0 = ms*1024; m0 < ms*1024 + 1024; m0 += 64) {
        f32x4 s[4];
        #pragma unroll
        for (int mj = 0; mj < 4; mj++) {
            const bf16x8* kp = (const bf16x8*)&kT[((size_t)b*NPT + m0 + 16*mj + c16)*CQD + 8*q];
            f32x4 a = {0.f, 0.f, 0.f, 0.f};
            a = MFMA32(aq0, kp[0], a);
            a = MFMA32(aq1, kp[4], a);
            s[mj] = a;
        }
        #pragma unroll
        for (int r = 0; r < 4; r++) {
            rz[r] += EXP2F(s[0][r]*L2E) + EXP2F(s[1][r]*L2E)
                   + EXP2F(s[2][r]*L2E) + EXP2F(s[3][r]*L2E);
        }
    }
    #pragma unroll
    for (int r = 0; r < 4; r++) {
        float Z = rz[r];
        #pragma unroll
        for (int d = 1; d < 16; d <<= 1) Z += __shfl_xor(Z, d, 64);
        if (c16 == 0)
            psum[((size_t)(b*4 + ms))*NPT + nb + 4*q + r] = Z;
    }
}

// ---------------------------------------------------------------------------
// merge: Lrow[n] = log2(sum of 4 partial Z)
// ---------------------------------------------------------------------------
__global__ void merge_kernel(const float* __restrict__ psum, float* __restrict__ Lrow)
{
    const int g = blockIdx.x*256 + threadIdx.x;
    const int b = g >> 12;
    const int n = g & 4095;
    float Z = 0.f;
    #pragma unroll
    for (int s = 0; s < 4; s++) Z += psum[((size_t)(b*4+s))*NPT + n];
    Lrow[(size_t)b*NPT + n] = __log2f(Z);
}

// ---------------------------------------------------------------------------
// attn: QK computed ONCE per (b, m-slice of 32). 8 waves (512 thr), all 256
// channels per block (wave w owns c rows 32w..32w+31). m-tile 32 -> TWO
// blocks/CU; NO setprio (with 2 co-resident blocks, prio-1 PV starves the
// other block's QK/exp2 phase and serializes them — round-2 lesson).
// n'-tile = 256 rows/iter, 16 iters: round-1 MFMA density (40/wave/iter)
// at HALF of round 1's barrier count; cross-block overlap fills the drains.
// p LDS layout: unit u = g*2 + mj (g = n'/4 within tile, 0..63), addr
// U = u*18 + c16, uint2 = 4 n' rows x 1 m-col, stride-18 units (bank-clean).
// Writer: g = 4w + q + 32*ng2. Reader (kc 0..7): g = 8kc + 2q (+1).
// One barrier/iter, double-buffered. grid 512 = 4b x 128mt, XCD-grouped by b
// (per-XCD set: v 2MB + q 512KB + k-slice 256KB fits 4MB L2). block 512.
// ---------------------------------------------------------------------------
__global__ __launch_bounds__(512, 4) void attn_kernel(
    const u16* __restrict__ qT, const u16* __restrict__ kT, const u16* __restrict__ vbf,
    const float* __restrict__ Lrow, const float* __restrict__ gamma,
    const float* __restrict__ x, float* __restrict__ out)
{
    __shared__ uint2 p_l[2][2304];   // 2 x 18432 B

    const int t = threadIdx.x;
    const int w = t >> 6, l = t & 63, q = l >> 4, c16 = l & 15;

    const int id  = blockIdx.x;
    const int xcd = id & 7;                    // dispatch round-robins XCDs
    const int jb  = id >> 3;                   // 0..63
    const int b   = xcd >> 1;                  // 2 XCDs per batch -> L2 locality
    const int mt  = ((xcd & 1) << 6) | jb;     // 64 m-tiles per XCD
    const int m0  = mt * 32;

    // persistent k B-fragments: m = m0 + 16*mj + c16, K=64 over o
    bf16x8 kf[2][2];
    #pragma unroll
    for (int mj = 0; mj < 2; mj++) {
        const bf16x8* kp = (const bf16x8*)&kT[((size_t)b*NPT + m0 + 16*mj + c16)*CQD + 8*q];
        kf[mj][0] = kp[0];
        kf[mj][1] = kp[4];
    }

    f32x4 acc[2][2];   // [cg][mj]: c = 32w + 16cg + 4q + r, m = m0 + 16mj + c16
    #pragma unroll
    for (int cg = 0; cg < 2; cg++)
        #pragma unroll
        for (int mj = 0; mj < 2; mj++)
            acc[cg][mj] = (f32x4){0.f, 0.f, 0.f, 0.f};

    const u16*   qrow  = &qT[((size_t)b*NPT + 16*w + c16)*CQD + 8*q];
    const float* Lb    = &Lrow[(size_t)b*NPT + 16*w + 4*q];
    const u16*   vrow0 = &vbf[((size_t)(b*C_IN + 32*w + c16))*NPT + 8*q];
    const u16*   vrow1 = vrow0 + (size_t)16*NPT;

    // LDS unit indices (stride-18 units of uint2)
    const int Uw = (8*w + 2*q)*18 + c16;       // + (64*ng2 + mj)*18
    const int Ur = (4*q)*18 + c16;             // + (16*kc + mj)*18, +36 for rows+4

    // q A-fragments: ng2=0 -> rows 16w+c16, ng2=1 -> rows 128+16w+c16
    bf16x8 qa[2][2];
    qa[0][0] = *(const bf16x8*)qrow;
    qa[0][1] = *(const bf16x8*)(qrow + 32);
    qa[1][0] = *(const bf16x8*)(qrow + (size_t)128*CQD);
    qa[1][1] = *(const bf16x8*)(qrow + (size_t)128*CQD + 32);

    int buf = 0;
    for (int nt = 0; nt < 16; nt++) {
        const int n0 = nt * 256;

        // s: wave's 32 n' rows (two 16-row groups) x 32 m (K=64)
        f32x4 s[2][2];
        #pragma unroll
        for (int ng = 0; ng < 2; ng++)
            #pragma unroll
            for (int mj = 0; mj < 2; mj++) {
                f32x4 a = {0.f, 0.f, 0.f, 0.f};
                a = MFMA32(qa[ng][0], kf[mj][0], a);
                a = MFMA32(qa[ng][1], kf[mj][1], a);
                s[ng][mj] = a;
            }
        if (nt < 15) {   // prefetch next q fragments
            qa[0][0] = *(const bf16x8*)(qrow + (size_t)(n0 + 256)*CQD);
            qa[0][1] = *(const bf16x8*)(qrow + (size_t)(n0 + 256)*CQD + 32);
            qa[1][0] = *(const bf16x8*)(qrow + (size_t)(n0 + 384)*CQD);
            qa[1][1] = *(const bf16x8*)(qrow + (size_t)(n0 + 384)*CQD + 32);
        }
        const float4 Lr0 = *(const float4*)(Lb + n0);
        const float4 Lr1 = *(const float4*)(Lb + n0 + 128);

        // p = exp2(s*L2E - Lrow), trunc-pack, store flat units
        #pragma unroll
        for (int ng = 0; ng < 2; ng++) {
            const float4 Lr = ng ? Lr1 : Lr0;
            #pragma unroll
            for (int mj = 0; mj < 2; mj++) {
                const float p0 = EXP2F(s[ng][mj][0]*L2E - Lr.x);
                const float p1 = EXP2F(s[ng][mj][1]*L2E - Lr.y);
                const float p2 = EXP2F(s[ng][mj][2]*L2E - Lr.z);
                const float p3 = EXP2F(s[ng][mj][3]*L2E - Lr.w);
                uint2 u;
                u.x = pack_trunc(p0, p1);
                u.y = pack_trunc(p2, p3);
                p_l[buf][Uw + (64*ng + mj)*18] = u;
            }
        }
        __syncthreads();

        // PV: K=256 as 8 chunks of 32; va streamed per chunk (L2-resident),
        // B-frag shared across both channel groups
        #pragma unroll
        for (int kc = 0; kc < 8; kc++) {
            const bf16x8 va0 = *(const bf16x8*)(vrow0 + n0 + 32*kc);
            const bf16x8 va1 = *(const bf16x8*)(vrow1 + n0 + 32*kc);
            #pragma unroll
            for (int mj = 0; mj < 2; mj++) {
                const uint2 u0 = p_l[buf][Ur + (16*kc + mj)*18];
                const uint2 u1 = p_l[buf][Ur + (16*kc + mj)*18 + 36];
                uint4 f = make_uint4(u0.x, u0.y, u1.x, u1.y);
                const bf16x8 pf = *(bf16x8*)&f;
                acc[0][mj] = MFMA32(va0, pf, acc[0][mj]);
                acc[1][mj] = MFMA32(va1, pf, acc[1][mj]);
            }
        }
        buf ^= 1;
    }

    const float g = gamma[0];
    #pragma unroll
    for (int cg = 0; cg < 2; cg++)
        #pragma unroll
        for (int mj = 0; mj < 2; mj++)
            #pragma unroll
            for (int r = 0; r < 4; r++) {
                const size_t o = ((size_t)(b*C_IN + 32*w + 16*cg + 4*q + r))*NPT
                               + m0 + 16*mj + c16;
                out[o] = g*acc[cg][mj][r] + x[o];
            }
}

// ---------------------------------------------------------------------------
extern "C" void kernel_launch(void* const* d_in, const int* in_sizes, int n_in,
                              void* d_out, int out_size, void* d_ws, size_t ws_size,
                              hipStream_t stream)
{
    const float* x     = (const float*)d_in[0];
    const float* wq    = (const float*)d_in[1];
    const float* bq    = (const float*)d_in[2];
    const float* wk    = (const float*)d_in[3];
    const float* bk    = (const float*)d_in[4];
    const float* wv    = (const float*)d_in[5];
    const float* bv    = (const float*)d_in[6];
    const float* gamma = (const float*)d_in[7];
    float* out = (float*)d_out;

    u16* qT  = (u16*)d_ws;                              // 2 MB
    u16* kT  = qT  + (size_t)NB*NPT*CQD;                // 2 MB
    u16* vbf = kT  + (size_t)NB*NPT*CQD;                // 8 MB
    u16* wbf = vbf + (size_t)NB*C_IN*NPT;               // 192 KB
    float* fp    = (float*)(wbf + 384*256);
    float* bias  = fp;                                  // 384
    float* psum  = bias + 384;                          // 64 KB
    float* Lrow  = psum + (size_t)NB*4*NPT;             // 64 KB

    prep_kernel<<<dim3(386), 256, 0, stream>>>(wq, bq, wk, bk, wv, bv, wbf, bias);
    proj_kernel<<<dim3(NPT/32, NB), 256, 0, stream>>>(x, wbf, bias, qT, kT, vbf);
    stats_kernel<<<dim3(4, NPT/64, NB), 256, 0, stream>>>(qT, kT, psum);
    merge_kernel<<<dim3(64), 256, 0, stream>>>(psum, Lrow);
    attn_kernel<<<dim3(512), 512, 0, stream>>>(qT, kT, vbf, Lrow, gamma, x, out);
}

// Round 5
// 242.508 us; speedup vs baseline: 1.2814x; 1.2814x over previous
//
#include <hip/hip_runtime.h>

#define NB   4
#define C_IN 256
#define CQD  64
#define NPT  4096
#define L2E  1.44269504088896f

typedef __attribute__((ext_vector_type(8))) short bf16x8;
typedef __attribute__((ext_vector_type(4))) float f32x4;
typedef unsigned short u16;
typedef unsigned int   u32;

#define EXP2F(x)      __builtin_amdgcn_exp2f(x)
#define MFMA32(A,B,C) __builtin_amdgcn_mfma_f32_16x16x32_bf16(A,B,C,0,0,0)

__device__ __forceinline__ u16 f2bf(float f) {          // RNE (cold paths)
    u32 u = __float_as_uint(f);
    u += 0x7fff + ((u >> 16) & 1);
    return (u16)(u >> 16);
}
// one v_perm: (bf16_trunc(hi)<<16) | bf16_trunc(lo)
__device__ __forceinline__ u32 pack_trunc(float lo, float hi) {
    return __builtin_amdgcn_perm(__float_as_uint(hi), __float_as_uint(lo), 0x07060302u);
}

// ---------------------------------------------------------------------------
// prep: pack wq|wk|wv into bf16 wbf[384][256], biases into bias[384]
// ---------------------------------------------------------------------------
__global__ void prep_kernel(
    const float* __restrict__ wq, const float* __restrict__ bq,
    const float* __restrict__ wk, const float* __restrict__ bk,
    const float* __restrict__ wv, const float* __restrict__ bv,
    u16* __restrict__ wbf, float* __restrict__ bias)
{
    const int gid = blockIdx.x*256 + threadIdx.x;
    if (gid < 384*256) {
        const int r = gid >> 8, c = gid & 255;
        const float v = (r < 64) ? wq[r*256 + c]
                      : (r < 128) ? wk[(r-64)*256 + c]
                                  : wv[(r-128)*256 + c];
        wbf[gid] = f2bf(v);
    } else if (gid < 384*256 + 384) {
        const int r = gid - 384*256;
        bias[r] = (r < 64) ? bq[r] : (r < 128) ? bk[r-64] : bv[r-128];
    }
}

// ---------------------------------------------------------------------------
// proj: MFMA pointwise projections, x read ONCE. Wave w owns tiles T=4*ot+w.
// grid (N/32, B), block 256.
// ---------------------------------------------------------------------------
union ProjShared {
    u16 x_t[32][264];                            // [n][c] bf16, stride 528B
    struct { u16 qk[32][136]; u16 vl[256][40]; } ep;
};

__global__ __launch_bounds__(256) void proj_kernel(
    const float* __restrict__ x, const u16* __restrict__ wbf,
    const float* __restrict__ bias,
    u16* __restrict__ qT, u16* __restrict__ kT, u16* __restrict__ vbf)
{
    __shared__ ProjShared sh;

    const int t  = threadIdx.x;
    const int n0 = blockIdx.x * 32;
    const int b  = blockIdx.y;

    {   // stage x tile transposed -> bf16 LDS
        const int ln = t & 31;
        const int cg = t >> 5;
        #pragma unroll
        for (int rr = 0; rr < 8; rr++) {
            const int c = 4*cg + 32*rr;
            const float f0 = x[((size_t)(b*C_IN + c+0))*NPT + n0 + ln];
            const float f1 = x[((size_t)(b*C_IN + c+1))*NPT + n0 + ln];
            const float f2 = x[((size_t)(b*C_IN + c+2))*NPT + n0 + ln];
            const float f3 = x[((size_t)(b*C_IN + c+3))*NPT + n0 + ln];
            ushort4 u4;
            u4.x = f2bf(f0); u4.y = f2bf(f1); u4.z = f2bf(f2); u4.w = f2bf(f3);
            *(ushort4*)&sh.x_t[ln][c] = u4;
        }
    }
    __syncthreads();

    const int w = t >> 6, l = t & 63, q = l >> 4, c16 = l & 15;

    f32x4 acc[6][2];
    #pragma unroll
    for (int ot = 0; ot < 6; ot++)
        #pragma unroll
        for (int nt = 0; nt < 2; nt++)
            acc[ot][nt] = (f32x4){0.f, 0.f, 0.f, 0.f};

    #pragma unroll
    for (int kk = 0; kk < 8; kk++) {
        const bf16x8 bf0 = *(const bf16x8*)&sh.x_t[c16     ][kk*32 + 8*q];
        const bf16x8 bf1 = *(const bf16x8*)&sh.x_t[16 + c16][kk*32 + 8*q];
        #pragma unroll
        for (int ot = 0; ot < 6; ot++) {
            const int o = 16*(4*ot + w) + c16;
            const bf16x8 af = *(const bf16x8*)&wbf[(size_t)o*C_IN + kk*32 + 8*q];
            acc[ot][0] = MFMA32(af, bf0, acc[ot][0]);
            acc[ot][1] = MFMA32(af, bf1, acc[ot][1]);
        }
    }
    __syncthreads();   // x_t dead; reuse LDS for epilogue staging

    #pragma unroll
    for (int ot = 0; ot < 6; ot++) {
        const int T  = 4*ot + w;
        const int ob = 16*T + 4*q;
        float b0 = bias[ob+0], b1 = bias[ob+1], b2 = bias[ob+2], b3 = bias[ob+3];
        #pragma unroll
        for (int nt = 0; nt < 2; nt++) {
            const f32x4 a = acc[ot][nt];
            const float v0 = a[0]+b0, v1 = a[1]+b1, v2 = a[2]+b2, v3 = a[3]+b3;
            if (ot < 2) {
                uint2 u;
                u.x = (u32)f2bf(v0) | ((u32)f2bf(v1) << 16);
                u.y = (u32)f2bf(v2) | ((u32)f2bf(v3) << 16);
                *(uint2*)&sh.ep.qk[16*nt + c16][16*T + 4*q] = u;
            } else {
                const int cb = 16*T - 128 + 4*q;
                sh.ep.vl[cb+0][16*nt + c16] = f2bf(v0);
                sh.ep.vl[cb+1][16*nt + c16] = f2bf(v1);
                sh.ep.vl[cb+2][16*nt + c16] = f2bf(v2);
                sh.ep.vl[cb+3][16*nt + c16] = f2bf(v3);
            }
        }
    }
    __syncthreads();

    {   // coalesced global stores
        const int n  = t >> 3;
        const int o8 = (t & 7) * 8;
        *(uint4*)&qT[((size_t)b*NPT + n0 + n)*CQD + o8] = *(uint4*)&sh.ep.qk[n][o8];
        *(uint4*)&kT[((size_t)b*NPT + n0 + n)*CQD + o8] = *(uint4*)&sh.ep.qk[n][64 + o8];
        u16* vrow = &vbf[((size_t)b*C_IN + t)*NPT + n0];
        #pragma unroll
        for (int j = 0; j < 4; j++)
            *(uint4*)&vrow[8*j] = *(uint4*)&sh.ep.vl[t][8*j];
    }
}

// ---------------------------------------------------------------------------
// stats: no-max partial softmax sums over 1024-wide m-split via MFMA.
// k fragments software-pipelined one m-step ahead (hide L2 latency).
// grid (4 msplit, N/64, B), block 256.
// ---------------------------------------------------------------------------
__global__ __launch_bounds__(256, 4) void stats_kernel(
    const u16* __restrict__ qT, const u16* __restrict__ kT,
    float* __restrict__ psum)
{
    const int t = threadIdx.x;
    const int w = t >> 6, l = t & 63, q = l >> 4, c16 = l & 15;
    const int ms = blockIdx.x, nt = blockIdx.y, b = blockIdx.z;
    const int nb = nt*64 + 16*w;

    const bf16x8* qp = (const bf16x8*)&qT[((size_t)b*NPT + nb + c16)*CQD + 8*q];
    const bf16x8 aq0 = qp[0];
    const bf16x8 aq1 = qp[4];

    float rz[4] = {0.f, 0.f, 0.f, 0.f};

    const int mbeg = ms*1024, mend = mbeg + 1024;

    // preload k fragments for first m-step
    bf16x8 kc0[4], kc1[4];
    #pragma unroll
    for (int mj = 0; mj < 4; mj++) {
        const bf16x8* kp = (const bf16x8*)&kT[((size_t)b*NPT + mbeg + 16*mj + c16)*CQD + 8*q];
        kc0[mj] = kp[0];
        kc1[mj] = kp[4];
    }

    for (int m0 = mbeg; m0 < mend; m0 += 64) {
        const int mn = (m0 + 64 < mend) ? m0 + 64 : mbeg;   // clamped prefetch
        bf16x8 kn0[4], kn1[4];
        #pragma unroll
        for (int mj = 0; mj < 4; mj++) {
            const bf16x8* kp = (const bf16x8*)&kT[((size_t)b*NPT + mn + 16*mj + c16)*CQD + 8*q];
            kn0[mj] = kp[0];
            kn1[mj] = kp[4];
        }

        f32x4 s[4];
        #pragma unroll
        for (int mj = 0; mj < 4; mj++) {
            f32x4 a = {0.f, 0.f, 0.f, 0.f};
            a = MFMA32(aq0, kc0[mj], a);
            a = MFMA32(aq1, kc1[mj], a);
            s[mj] = a;
        }
        #pragma unroll
        for (int r = 0; r < 4; r++) {
            rz[r] += EXP2F(s[0][r]*L2E) + EXP2F(s[1][r]*L2E)
                   + EXP2F(s[2][r]*L2E) + EXP2F(s[3][r]*L2E);
        }
        #pragma unroll
        for (int mj = 0; mj < 4; mj++) {
            kc0[mj] = kn0[mj];
            kc1[mj] = kn1[mj];
        }
    }
    #pragma unroll
    for (int r = 0; r < 4; r++) {
        float Z = rz[r];
        #pragma unroll
        for (int d = 1; d < 16; d <<= 1) Z += __shfl_xor(Z, d, 64);
        if (c16 == 0)
            psum[((size_t)(b*4 + ms))*NPT + nb + 4*q + r] = Z;
    }
}

// ---------------------------------------------------------------------------
// merge: Lrow[n] = log2(sum of 4 partial Z)
// ---------------------------------------------------------------------------
__global__ void merge_kernel(const float* __restrict__ psum, float* __restrict__ Lrow)
{
    const int g = blockIdx.x*256 + threadIdx.x;
    const int b = g >> 12;
    const int n = g & 4095;
    float Z = 0.f;
    #pragma unroll
    for (int s = 0; s < 4; s++) Z += psum[((size_t)(b*4+s))*NPT + n];
    Lrow[(size_t)b*NPT + n] = __log2f(Z);
}

// ---------------------------------------------------------------------------
// attn: round-1 geometry (m-tile 64, grid 256 = 1 block/CU, minimal v/q
// amplification — R2/R3 showed time scales with load:MFMA ratio, not
// barriers) + FULL register double-buffering: va (8x bf16x8) and Lr for
// iter nt+1 are loaded during iter nt (≈6700 cyc cover vs ~200 before).
// VGPR ~200 is free: 1 block/CU -> 2 waves/SIMD regardless (cap 256).
// p LDS layout (R1, verified): unit U(w,q,mj) = (w*16+q*4+mj)*17 + c16,
// uint2 = 4 n' rows x 1 m-col; reads 2-way-bank (free), writes 4-way.
// One barrier/iter, double-buffered p. grid 256 = 4b x 64mt XCD-grouped,
// block 512.
// ---------------------------------------------------------------------------
__global__ __launch_bounds__(512, 2) void attn_kernel(
    const u16* __restrict__ qT, const u16* __restrict__ kT, const u16* __restrict__ vbf,
    const float* __restrict__ Lrow, const float* __restrict__ gamma,
    const float* __restrict__ x, float* __restrict__ out)
{
    __shared__ uint2 p_l[2][2176];   // 2 x 17408 B

    const int t = threadIdx.x;
    const int w = t >> 6, l = t & 63, q = l >> 4, c16 = l & 15;

    const int id  = blockIdx.x;
    const int xcd = id & 7;                    // dispatch round-robins XCDs
    const int jb  = id >> 3;                   // 0..31
    const int b   = xcd >> 1;                  // 2 XCDs per batch -> L2 locality
    const int mt  = ((xcd & 1) << 5) | jb;     // 32 m-tiles per XCD
    const int m0  = mt * 64;

    // persistent k B-fragments: m = m0 + 16*mj + c16, K=64 over o
    bf16x8 kf[4][2];
    #pragma unroll
    for (int mj = 0; mj < 4; mj++) {
        const bf16x8* kp = (const bf16x8*)&kT[((size_t)b*NPT + m0 + 16*mj + c16)*CQD + 8*q];
        kf[mj][0] = kp[0];
        kf[mj][1] = kp[4];
    }

    f32x4 acc[2][4];   // [cg][mj]: c = 32w + 16cg + 4q + r, m = m0 + 16mj + c16
    #pragma unroll
    for (int cg = 0; cg < 2; cg++)
        #pragma unroll
        for (int mj = 0; mj < 4; mj++)
            acc[cg][mj] = (f32x4){0.f, 0.f, 0.f, 0.f};

    const u16*   qrow  = &qT[((size_t)b*NPT + 16*w + c16)*CQD + 8*q];
    const float* Lb    = &Lrow[(size_t)b*NPT + 16*w + 4*q];
    const u16*   vrow0 = &vbf[((size_t)(b*C_IN + 32*w + c16))*NPT + 8*q];
    const u16*   vrow1 = vrow0 + (size_t)16*NPT;

    // LDS unit indices (stride-17 units of uint2)
    const int Uw  = (w*16 + q*4)*17 + c16;                    // + mj*17
    const int Ur0 = ((q>>1)*16 + (q&1)*8)*17 + c16;           // + kc*544 + mj*17 (+68)

    bf16x8 qa0 = *(const bf16x8*)qrow;
    bf16x8 qa1 = *(const bf16x8*)(qrow + 32);

    // preload va fragments + Lr for iter 0
    bf16x8 vac0[4], vac1[4];
    #pragma unroll
    for (int kc = 0; kc < 4; kc++) {
        vac0[kc] = *(const bf16x8*)(vrow0 + 32*kc);
        vac1[kc] = *(const bf16x8*)(vrow1 + 32*kc);
    }
    float4 Lrc = *(const float4*)Lb;

    int buf = 0;
    for (int nt = 0; nt < 32; nt++) {
        const int n0 = nt * 128;
        const int n1 = (nt < 31) ? n0 + 128 : n0;   // clamped prefetch target

        // s: wave's 16 n' rows x 64 m (K=64)
        f32x4 s[4];
        #pragma unroll
        for (int mj = 0; mj < 4; mj++) {
            f32x4 a = {0.f, 0.f, 0.f, 0.f};
            a = MFMA32(qa0, kf[mj][0], a);
            a = MFMA32(qa1, kf[mj][1], a);
            s[mj] = a;
        }
        if (nt < 31) {   // prefetch next q fragment
            qa0 = *(const bf16x8*)(qrow + (size_t)(n0 + 128)*CQD);
            qa1 = *(const bf16x8*)(qrow + (size_t)(n0 + 128)*CQD + 32);
        }
        // prefetch NEXT iter's v fragments + Lr (consumed after next barrier)
        bf16x8 van0[4], van1[4];
        #pragma unroll
        for (int kc = 0; kc < 4; kc++) {
            van0[kc] = *(const bf16x8*)(vrow0 + n1 + 32*kc);
            van1[kc] = *(const bf16x8*)(vrow1 + n1 + 32*kc);
        }
        const float4 Lrn = *(const float4*)(Lb + n1);

        // p = exp2(s*L2E - Lrow), trunc-pack, store flat units (uses Lrc)
        #pragma unroll
        for (int mj = 0; mj < 4; mj++) {
            const float p0 = EXP2F(s[mj][0]*L2E - Lrc.x);
            const float p1 = EXP2F(s[mj][1]*L2E - Lrc.y);
            const float p2 = EXP2F(s[mj][2]*L2E - Lrc.z);
            const float p3 = EXP2F(s[mj][3]*L2E - Lrc.w);
            uint2 u;
            u.x = pack_trunc(p0, p1);
            u.y = pack_trunc(p2, p3);
            p_l[buf][Uw + mj*17] = u;
        }
        __syncthreads();

        // PV: K=128 as 4 chunks of 32, va already in registers
        __builtin_amdgcn_s_setprio(1);
        #pragma unroll
        for (int mj = 0; mj < 4; mj++) {
            #pragma unroll
            for (int kc = 0; kc < 4; kc++) {
                const uint2 u0 = p_l[buf][Ur0 + kc*544 + mj*17];
                const uint2 u1 = p_l[buf][Ur0 + kc*544 + mj*17 + 68];
                uint4 f = make_uint4(u0.x, u0.y, u1.x, u1.y);
                const bf16x8 pf = *(bf16x8*)&f;
                acc[0][mj] = MFMA32(vac0[kc], pf, acc[0][mj]);
                acc[1][mj] = MFMA32(vac1[kc], pf, acc[1][mj]);
            }
        }
        __builtin_amdgcn_s_setprio(0);

        // rotate prefetch buffers (compile-time indices; compiler renames)
        #pragma unroll
        for (int kc = 0; kc < 4; kc++) {
            vac0[kc] = van0[kc];
            vac1[kc] = van1[kc];
        }
        Lrc = Lrn;
        buf ^= 1;
    }

    const float g = gamma[0];
    #pragma unroll
    for (int cg = 0; cg < 2; cg++)
        #pragma unroll
        for (int mj = 0; mj < 4; mj++)
            #pragma unroll
            for (int r = 0; r < 4; r++) {
                const size_t o = ((size_t)(b*C_IN + 32*w + 16*cg + 4*q + r))*NPT
                               + m0 + 16*mj + c16;
                out[o] = g*acc[cg][mj][r] + x[o];
            }
}

// ---------------------------------------------------------------------------
extern "C" void kernel_launch(void* const* d_in, const int* in_sizes, int n_in,
                              void* d_out, int out_size, void* d_ws, size_t ws_size,
                              hipStream_t stream)
{
    const float* x     = (const float*)d_in[0];
    const float* wq    = (const float*)d_in[1];
    const float* bq    = (const float*)d_in[2];
    const float* wk    = (const float*)d_in[3];
    const float* bk    = (const float*)d_in[4];
    const float* wv    = (const float*)d_in[5];
    const float* bv    = (const float*)d_in[6];
    const float* gamma = (const float*)d_in[7];
    float* out = (float*)d_out;

    u16* qT  = (u16*)d_ws;                              // 2 MB
    u16* kT  = qT  + (size_t)NB*NPT*CQD;                // 2 MB
    u16* vbf = kT  + (size_t)NB*NPT*CQD;                // 8 MB
    u16* wbf = vbf + (size_t)NB*C_IN*NPT;               // 192 KB
    float* fp    = (float*)(wbf + 384*256);
    float* bias  = fp;                                  // 384
    float* psum  = bias + 384;                          // 64 KB
    float* Lrow  = psum + (size_t)NB*4*NPT;             // 64 KB

    prep_kernel<<<dim3(386), 256, 0, stream>>>(wq, bq, wk, bk, wv, bv, wbf, bias);
    proj_kernel<<<dim3(NPT/32, NB), 256, 0, stream>>>(x, wbf, bias, qT, kT, vbf);
    stats_kernel<<<dim3(4, NPT/64, NB), 256, 0, stream>>>(qT, kT, psum);
    merge_kernel<<<dim3(64), 256, 0, stream>>>(psum, Lrow);
    attn_kernel<<<dim3(256), 512, 0, stream>>>(qT, kT, vbf, Lrow, gamma, x, out);
}

// Round 6
// 171.669 us; speedup vs baseline: 1.8102x; 1.4126x over previous
//
#include <hip/hip_runtime.h>

#define NB   4
#define C_IN 256
#define CQD  64
#define NPT  4096
#define L2E  1.44269504088896f

typedef __attribute__((ext_vector_type(8))) short bf16x8;
typedef __attribute__((ext_vector_type(4))) float f32x4;
typedef unsigned short u16;
typedef unsigned int   u32;

#define EXP2F(x)      __builtin_amdgcn_exp2f(x)
#define MFMA32(A,B,C) __builtin_amdgcn_mfma_f32_16x16x32_bf16(A,B,C,0,0,0)

__device__ __forceinline__ u16 f2bf(float f) {          // RNE (cold paths)
    u32 u = __float_as_uint(f);
    u += 0x7fff + ((u >> 16) & 1);
    return (u16)(u >> 16);
}
// one v_perm: (bf16_trunc(hi)<<16) | bf16_trunc(lo)
__device__ __forceinline__ u32 pack_trunc(float lo, float hi) {
    return __builtin_amdgcn_perm(__float_as_uint(hi), __float_as_uint(lo), 0x07060302u);
}

// ---------------------------------------------------------------------------
// Fragment-major layouts (kills 16-way transaction amplification):
//   qF/kF: [b][g][half][lane][8] u16, g = seq/16, half = o-chunk/4,
//          lane = 16*q + c16 holds (row 16g+c16, o elems 8*(q+4*half)..+7).
//          u16 offset = (b*256+g)*1024 + half*512 + lane*8.   (2 MB each)
//   vF:    [b][cg][ng][lane][8] u16, cg = c/16, ng = n/32,
//          lane = 16*q + c16 holds (row 16cg+c16, n elems 32ng+8q..+7).
//          u16 offset = ((b*16+cg)*128+ng)*512 + lane*8.      (8 MB)
// Every fragment load is a lane-contiguous 1KB dwordx4 (1 request/wave).
// ---------------------------------------------------------------------------

// ---------------------------------------------------------------------------
// prep: pack wq|wk|wv into bf16 wbf[384][256], biases into bias[384]
// ---------------------------------------------------------------------------
__global__ void prep_kernel(
    const float* __restrict__ wq, const float* __restrict__ bq,
    const float* __restrict__ wk, const float* __restrict__ bk,
    const float* __restrict__ wv, const float* __restrict__ bv,
    u16* __restrict__ wbf, float* __restrict__ bias)
{
    const int gid = blockIdx.x*256 + threadIdx.x;
    if (gid < 384*256) {
        const int r = gid >> 8, c = gid & 255;
        const float v = (r < 64) ? wq[r*256 + c]
                      : (r < 128) ? wk[(r-64)*256 + c]
                                  : wv[(r-128)*256 + c];
        wbf[gid] = f2bf(v);
    } else if (gid < 384*256 + 384) {
        const int r = gid - 384*256;
        bias[r] = (r < 64) ? bq[r] : (r < 128) ? bk[r-64] : bv[r-128];
    }
}

// ---------------------------------------------------------------------------
// proj: MFMA pointwise projections, x read ONCE. Wave w owns tiles T=4*ot+w.
// grid (N/32, B), block 256. Epilogue stores in fragment-major layouts.
// ---------------------------------------------------------------------------
union ProjShared {
    u16 x_t[32][264];                            // [n][c] bf16, stride 528B
    struct { u16 qk[32][136]; u16 vl[256][40]; } ep;
};

__global__ __launch_bounds__(256) void proj_kernel(
    const float* __restrict__ x, const u16* __restrict__ wbf,
    const float* __restrict__ bias,
    u16* __restrict__ qF, u16* __restrict__ kF, u16* __restrict__ vF)
{
    __shared__ ProjShared sh;

    const int t  = threadIdx.x;
    const int n0 = blockIdx.x * 32;
    const int b  = blockIdx.y;

    {   // stage x tile transposed -> bf16 LDS
        const int ln = t & 31;
        const int cg = t >> 5;
        #pragma unroll
        for (int rr = 0; rr < 8; rr++) {
            const int c = 4*cg + 32*rr;
            const float f0 = x[((size_t)(b*C_IN + c+0))*NPT + n0 + ln];
            const float f1 = x[((size_t)(b*C_IN + c+1))*NPT + n0 + ln];
            const float f2 = x[((size_t)(b*C_IN + c+2))*NPT + n0 + ln];
            const float f3 = x[((size_t)(b*C_IN + c+3))*NPT + n0 + ln];
            ushort4 u4;
            u4.x = f2bf(f0); u4.y = f2bf(f1); u4.z = f2bf(f2); u4.w = f2bf(f3);
            *(ushort4*)&sh.x_t[ln][c] = u4;
        }
    }
    __syncthreads();

    const int w = t >> 6, l = t & 63, q = l >> 4, c16 = l & 15;

    f32x4 acc[6][2];
    #pragma unroll
    for (int ot = 0; ot < 6; ot++)
        #pragma unroll
        for (int nt = 0; nt < 2; nt++)
            acc[ot][nt] = (f32x4){0.f, 0.f, 0.f, 0.f};

    #pragma unroll
    for (int kk = 0; kk < 8; kk++) {
        const bf16x8 bf0 = *(const bf16x8*)&sh.x_t[c16     ][kk*32 + 8*q];
        const bf16x8 bf1 = *(const bf16x8*)&sh.x_t[16 + c16][kk*32 + 8*q];
        #pragma unroll
        for (int ot = 0; ot < 6; ot++) {
            const int o = 16*(4*ot + w) + c16;
            const bf16x8 af = *(const bf16x8*)&wbf[(size_t)o*C_IN + kk*32 + 8*q];
            acc[ot][0] = MFMA32(af, bf0, acc[ot][0]);
            acc[ot][1] = MFMA32(af, bf1, acc[ot][1]);
        }
    }
    __syncthreads();   // x_t dead; reuse LDS for epilogue staging

    #pragma unroll
    for (int ot = 0; ot < 6; ot++) {
        const int T  = 4*ot + w;
        const int ob = 16*T + 4*q;
        float b0 = bias[ob+0], b1 = bias[ob+1], b2 = bias[ob+2], b3 = bias[ob+3];
        #pragma unroll
        for (int nt = 0; nt < 2; nt++) {
            const f32x4 a = acc[ot][nt];
            const float v0 = a[0]+b0, v1 = a[1]+b1, v2 = a[2]+b2, v3 = a[3]+b3;
            if (ot < 2) {
                uint2 u;
                u.x = (u32)f2bf(v0) | ((u32)f2bf(v1) << 16);
                u.y = (u32)f2bf(v2) | ((u32)f2bf(v3) << 16);
                *(uint2*)&sh.ep.qk[16*nt + c16][16*T + 4*q] = u;
            } else {
                const int cb = 16*T - 128 + 4*q;
                sh.ep.vl[cb+0][16*nt + c16] = f2bf(v0);
                sh.ep.vl[cb+1][16*nt + c16] = f2bf(v1);
                sh.ep.vl[cb+2][16*nt + c16] = f2bf(v2);
                sh.ep.vl[cb+3][16*nt + c16] = f2bf(v3);
            }
        }
    }
    __syncthreads();

    {   // fragment-major global stores
        // q/k: thread t -> local row n = t>>3, o-chunk c = t&7
        const int n    = t >> 3;
        const int c    = t & 7;
        const int g    = (n0 + n) >> 4;
        const int lane = 16*(c & 3) + (n & 15);
        const size_t dq = ((size_t)(b*256 + g))*1024 + (size_t)(c >> 2)*512 + lane*8;
        *(uint4*)&qF[dq] = *(uint4*)&sh.ep.qk[n][8*c];
        *(uint4*)&kF[dq] = *(uint4*)&sh.ep.qk[n][64 + 8*c];
        // v: thread t = c-row; tile covers one n-group ng = n0/32
        const int cg   = t >> 4, c16v = t & 15;
        const int ng   = n0 >> 5;
        u16* vdst = &vF[(((size_t)(b*16 + cg))*128 + ng)*512 + c16v*8];
        #pragma unroll
        for (int j = 0; j < 4; j++)          // lane 16j+c16v -> offset j*128
            *(uint4*)&vdst[j*128] = *(uint4*)&sh.ep.vl[t][8*j];
    }
}

// ---------------------------------------------------------------------------
// stats: no-max partial softmax sums over 1024-wide m-split via MFMA.
// Fragment-major coalesced loads; k pipelined one m-step ahead.
// grid (4 msplit, N/64, B), block 256.
// ---------------------------------------------------------------------------
__global__ __launch_bounds__(256, 4) void stats_kernel(
    const u16* __restrict__ qF, const u16* __restrict__ kF,
    float* __restrict__ psum)
{
    const int t = threadIdx.x;
    const int w = t >> 6, l = t & 63, q = l >> 4, c16 = l & 15;
    const int ms = blockIdx.x, nt = blockIdx.y, b = blockIdx.z;
    const int nb = nt*64 + 16*w;

    const u16* qp = &qF[((size_t)(b*256 + nt*4 + w))*1024 + l*8];
    const bf16x8 aq0 = *(const bf16x8*)qp;
    const bf16x8 aq1 = *(const bf16x8*)(qp + 512);

    float rz[4] = {0.f, 0.f, 0.f, 0.f};

    const int mbeg = ms*1024, mend = mbeg + 1024;
    const u16* kbase = &kF[((size_t)b*256)*1024 + l*8];

    // preload k fragments for first m-step
    bf16x8 kc0[4], kc1[4];
    #pragma unroll
    for (int mj = 0; mj < 4; mj++) {
        const u16* kp = kbase + (size_t)((mbeg >> 4) + mj)*1024;
        kc0[mj] = *(const bf16x8*)kp;
        kc1[mj] = *(const bf16x8*)(kp + 512);
    }

    for (int m0 = mbeg; m0 < mend; m0 += 64) {
        const int mn = (m0 + 64 < mend) ? m0 + 64 : mbeg;   // clamped prefetch
        bf16x8 kn0[4], kn1[4];
        #pragma unroll
        for (int mj = 0; mj < 4; mj++) {
            const u16* kp = kbase + (size_t)((mn >> 4) + mj)*1024;
            kn0[mj] = *(const bf16x8*)kp;
            kn1[mj] = *(const bf16x8*)(kp + 512);
        }

        f32x4 s[4];
        #pragma unroll
        for (int mj = 0; mj < 4; mj++) {
            f32x4 a = {0.f, 0.f, 0.f, 0.f};
            a = MFMA32(aq0, kc0[mj], a);
            a = MFMA32(aq1, kc1[mj], a);
            s[mj] = a;
        }
        #pragma unroll
        for (int r = 0; r < 4; r++) {
            rz[r] += EXP2F(s[0][r]*L2E) + EXP2F(s[1][r]*L2E)
                   + EXP2F(s[2][r]*L2E) + EXP2F(s[3][r]*L2E);
        }
        #pragma unroll
        for (int mj = 0; mj < 4; mj++) {
            kc0[mj] = kn0[mj];
            kc1[mj] = kn1[mj];
        }
    }
    #pragma unroll
    for (int r = 0; r < 4; r++) {
        float Z = rz[r];
        #pragma unroll
        for (int d = 1; d < 16; d <<= 1) Z += __shfl_xor(Z, d, 64);
        if (c16 == 0)
            psum[((size_t)(b*4 + ms))*NPT + nb + 4*q + r] = Z;
    }
}

// ---------------------------------------------------------------------------
// merge: Lrow[n] = log2(sum of 4 partial Z)
// ---------------------------------------------------------------------------
__global__ void merge_kernel(const float* __restrict__ psum, float* __restrict__ Lrow)
{
    const int g = blockIdx.x*256 + threadIdx.x;
    const int b = g >> 12;
    const int n = g & 4095;
    float Z = 0.f;
    #pragma unroll
    for (int s = 0; s < 4; s++) Z += psum[((size_t)(b*4+s))*NPT + n];
    Lrow[(size_t)b*NPT + n] = __log2f(Z);
}

// ---------------------------------------------------------------------------
// attn: R5 structure (m-tile 64, 1 blk/CU, reg-dbuf va/Lr) with fragment-
// major coalesced loads — every q/k/v fragment load is one lane-contiguous
// 1KB dwordx4 (was 16 scattered 64B segments; load-issue rate was the
// measured invariant ~31/µs/CU binding R1/R3/R5).
// p LDS layout (verified): unit U(w,q,mj) = (w*16+q*4+mj)*17 + c16,
// uint2 = 4 n' rows x 1 m-col; reads 2-way-bank (free), writes 4-way.
// One barrier/iter, double-buffered p. grid 256 = 4b x 64mt XCD-grouped,
// block 512.
// ---------------------------------------------------------------------------
__global__ __launch_bounds__(512, 2) void attn_kernel(
    const u16* __restrict__ qF, const u16* __restrict__ kF, const u16* __restrict__ vF,
    const float* __restrict__ Lrow, const float* __restrict__ gamma,
    const float* __restrict__ x, float* __restrict__ out)
{
    __shared__ uint2 p_l[2][2176];   // 2 x 17408 B

    const int t = threadIdx.x;
    const int w = t >> 6, l = t & 63, q = l >> 4, c16 = l & 15;

    const int id  = blockIdx.x;
    const int xcd = id & 7;                    // dispatch round-robins XCDs
    const int jb  = id >> 3;                   // 0..31
    const int b   = xcd >> 1;                  // 2 XCDs per batch -> L2 locality
    const int mt  = ((xcd & 1) << 5) | jb;     // 32 m-tiles per XCD
    const int m0  = mt * 64;

    // persistent k B-fragments: group gm = mt*4+mj
    bf16x8 kf[4][2];
    #pragma unroll
    for (int mj = 0; mj < 4; mj++) {
        const u16* kp = &kF[((size_t)(b*256 + mt*4 + mj))*1024 + l*8];
        kf[mj][0] = *(const bf16x8*)kp;
        kf[mj][1] = *(const bf16x8*)(kp + 512);
    }

    f32x4 acc[2][4];   // [cg][mj]: c = 32w + 16cg + 4q + r, m = m0 + 16mj + c16
    #pragma unroll
    for (int cg = 0; cg < 2; cg++)
        #pragma unroll
        for (int mj = 0; mj < 4; mj++)
            acc[cg][mj] = (f32x4){0.f, 0.f, 0.f, 0.f};

    // fragment-major bases (all lane-contiguous)
    const u16*   qbase  = &qF[((size_t)(b*256 + w))*1024 + l*8];        // + nt*8192
    const u16*   vbase0 = &vF[(((size_t)(b*16 + 2*w))*128)*512 + l*8];  // + (nt*4+kc)*512
    const u16*   vbase1 = vbase0 + (size_t)128*512;                     // cg+1
    const float* Lb     = &Lrow[(size_t)b*NPT + 16*w + 4*q];

    // LDS unit indices (stride-17 units of uint2)
    const int Uw  = (w*16 + q*4)*17 + c16;                    // + mj*17
    const int Ur0 = ((q>>1)*16 + (q&1)*8)*17 + c16;           // + kc*544 + mj*17 (+68)

    bf16x8 qa0 = *(const bf16x8*)qbase;
    bf16x8 qa1 = *(const bf16x8*)(qbase + 512);

    // preload va fragments + Lr for iter 0
    bf16x8 vac0[4], vac1[4];
    #pragma unroll
    for (int kc = 0; kc < 4; kc++) {
        vac0[kc] = *(const bf16x8*)(vbase0 + (size_t)kc*512);
        vac1[kc] = *(const bf16x8*)(vbase1 + (size_t)kc*512);
    }
    float4 Lrc = *(const float4*)Lb;

    int buf = 0;
    for (int nt = 0; nt < 32; nt++) {
        const int n0  = nt * 128;
        const int ntn = (nt < 31) ? nt + 1 : nt;    // clamped prefetch target

        // s: wave's 16 n' rows x 64 m (K=64)
        f32x4 s[4];
        #pragma unroll
        for (int mj = 0; mj < 4; mj++) {
            f32x4 a = {0.f, 0.f, 0.f, 0.f};
            a = MFMA32(qa0, kf[mj][0], a);
            a = MFMA32(qa1, kf[mj][1], a);
            s[mj] = a;
        }
        if (nt < 31) {   // prefetch next q fragment
            qa0 = *(const bf16x8*)(qbase + (size_t)(nt+1)*8192);
            qa1 = *(const bf16x8*)(qbase + (size_t)(nt+1)*8192 + 512);
        }
        // prefetch NEXT iter's v fragments + Lr (consumed after next barrier)
        bf16x8 van0[4], van1[4];
        #pragma unroll
        for (int kc = 0; kc < 4; kc++) {
            van0[kc] = *(const bf16x8*)(vbase0 + (size_t)(ntn*4 + kc)*512);
            van1[kc] = *(const bf16x8*)(vbase1 + (size_t)(ntn*4 + kc)*512);
        }
        const float4 Lrn = *(const float4*)(Lb + ntn*128);

        // p = exp2(s*L2E - Lrow), trunc-pack, store flat units (uses Lrc)
        #pragma unroll
        for (int mj = 0; mj < 4; mj++) {
            const float p0 = EXP2F(s[mj][0]*L2E - Lrc.x);
            const float p1 = EXP2F(s[mj][1]*L2E - Lrc.y);
            const float p2 = EXP2F(s[mj][2]*L2E - Lrc.z);
            const float p3 = EXP2F(s[mj][3]*L2E - Lrc.w);
            uint2 u;
            u.x = pack_trunc(p0, p1);
            u.y = pack_trunc(p2, p3);
            p_l[buf][Uw + mj*17] = u;
        }
        __syncthreads();

        // PV: K=128 as 4 chunks of 32, va already in registers
        __builtin_amdgcn_s_setprio(1);
        #pragma unroll
        for (int mj = 0; mj < 4; mj++) {
            #pragma unroll
            for (int kc = 0; kc < 4; kc++) {
                const uint2 u0 = p_l[buf][Ur0 + kc*544 + mj*17];
                const uint2 u1 = p_l[buf][Ur0 + kc*544 + mj*17 + 68];
                uint4 f = make_uint4(u0.x, u0.y, u1.x, u1.y);
                const bf16x8 pf = *(bf16x8*)&f;
                acc[0][mj] = MFMA32(vac0[kc], pf, acc[0][mj]);
                acc[1][mj] = MFMA32(vac1[kc], pf, acc[1][mj]);
            }
        }
        __builtin_amdgcn_s_setprio(0);

        // rotate prefetch buffers (compile-time indices; compiler renames)
        #pragma unroll
        for (int kc = 0; kc < 4; kc++) {
            vac0[kc] = van0[kc];
            vac1[kc] = van1[kc];
        }
        Lrc = Lrn;
        buf ^= 1;
    }

    const float g = gamma[0];
    #pragma unroll
    for (int cg = 0; cg < 2; cg++)
        #pragma unroll
        for (int mj = 0; mj < 4; mj++)
            #pragma unroll
            for (int r = 0; r < 4; r++) {
                const size_t o = ((size_t)(b*C_IN + 32*w + 16*cg + 4*q + r))*NPT
                               + m0 + 16*mj + c16;
                out[o] = g*acc[cg][mj][r] + x[o];
            }
}

// ---------------------------------------------------------------------------
extern "C" void kernel_launch(void* const* d_in, const int* in_sizes, int n_in,
                              void* d_out, int out_size, void* d_ws, size_t ws_size,
                              hipStream_t stream)
{
    const float* x     = (const float*)d_in[0];
    const float* wq    = (const float*)d_in[1];
    const float* bq    = (const float*)d_in[2];
    const float* wk    = (const float*)d_in[3];
    const float* bk    = (const float*)d_in[4];
    const float* wv    = (const float*)d_in[5];
    const float* bv    = (const float*)d_in[6];
    const float* gamma = (const float*)d_in[7];
    float* out = (float*)d_out;

    u16* qF  = (u16*)d_ws;                              // 2 MB
    u16* kF  = qF  + (size_t)NB*NPT*CQD;                // 2 MB
    u16* vF  = kF  + (size_t)NB*NPT*CQD;                // 8 MB
    u16* wbf = vF  + (size_t)NB*C_IN*NPT;               // 192 KB
    float* fp    = (float*)(wbf + 384*256);
    float* bias  = fp;                                  // 384
    float* psum  = bias + 384;                          // 64 KB
    float* Lrow  = psum + (size_t)NB*4*NPT;             // 64 KB

    prep_kernel<<<dim3(386), 256, 0, stream>>>(wq, bq, wk, bk, wv, bv, wbf, bias);
    proj_kernel<<<dim3(NPT/32, NB), 256, 0, stream>>>(x, wbf, bias, qF, kF, vF);
    stats_kernel<<<dim3(4, NPT/64, NB), 256, 0, stream>>>(qF, kF, psum);
    merge_kernel<<<dim3(64), 256, 0, stream>>>(psum, Lrow);
    attn_kernel<<<dim3(256), 512, 0, stream>>>(qF, kF, vF, Lrow, gamma, x, out);
}

// Round 7
// 166.609 us; speedup vs baseline: 1.8652x; 1.0304x over previous
//
#include <hip/hip_runtime.h>

#define NB   4
#define C_IN 256
#define CQD  64
#define NPT  4096
#define L2E  1.44269504088896f

typedef __attribute__((ext_vector_type(8))) short bf16x8;
typedef __attribute__((ext_vector_type(4))) float f32x4;
typedef unsigned short u16;
typedef unsigned int   u32;

#define EXP2F(x)      __builtin_amdgcn_exp2f(x)
#define MFMA32(A,B,C) __builtin_amdgcn_mfma_f32_16x16x32_bf16(A,B,C,0,0,0)

__device__ __forceinline__ u16 f2bf(float f) {          // RNE (cold paths)
    u32 u = __float_as_uint(f);
    u += 0x7fff + ((u >> 16) & 1);
    return (u16)(u >> 16);
}
// one v_perm: (bf16_trunc(hi)<<16) | bf16_trunc(lo)
__device__ __forceinline__ u32 pack_trunc(float lo, float hi) {
    return __builtin_amdgcn_perm(__float_as_uint(hi), __float_as_uint(lo), 0x07060302u);
}

// ---------------------------------------------------------------------------
// Fragment-major layouts (1 request per wave fragment load):
//   qF/kF: [b][g][half][lane][8] u16, g = seq/16, half = o-chunk/4,
//          lane = 16*q + c16 holds (row 16g+c16, o elems 8*(q+4*half)..+7).
//   vF:    [b][cg][ng][lane][8] u16, cg = c/16, ng = n/32,
//          lane = 16*q + c16 holds (row 16cg+c16, n elems 32ng+8q..+7).
// ---------------------------------------------------------------------------

// ---------------------------------------------------------------------------
// prep: pack wq|wk|wv into bf16 wbf[384][256], biases into bias[384]
// ---------------------------------------------------------------------------
__global__ void prep_kernel(
    const float* __restrict__ wq, const float* __restrict__ bq,
    const float* __restrict__ wk, const float* __restrict__ bk,
    const float* __restrict__ wv, const float* __restrict__ bv,
    u16* __restrict__ wbf, float* __restrict__ bias)
{
    const int gid = blockIdx.x*256 + threadIdx.x;
    if (gid < 384*256) {
        const int r = gid >> 8, c = gid & 255;
        const float v = (r < 64) ? wq[r*256 + c]
                      : (r < 128) ? wk[(r-64)*256 + c]
                                  : wv[(r-128)*256 + c];
        wbf[gid] = f2bf(v);
    } else if (gid < 384*256 + 384) {
        const int r = gid - 384*256;
        bias[r] = (r < 64) ? bq[r] : (r < 128) ? bk[r-64] : bv[r-128];
    }
}

// ---------------------------------------------------------------------------
// proj: MFMA pointwise projections, x read ONCE. Wave w owns tiles T=4*ot+w.
// grid (N/32, B), block 256. Epilogue stores in fragment-major layouts.
// ---------------------------------------------------------------------------
union ProjShared {
    u16 x_t[32][264];                            // [n][c] bf16, stride 528B
    struct { u16 qk[32][136]; u16 vl[256][40]; } ep;
};

__global__ __launch_bounds__(256) void proj_kernel(
    const float* __restrict__ x, const u16* __restrict__ wbf,
    const float* __restrict__ bias,
    u16* __restrict__ qF, u16* __restrict__ kF, u16* __restrict__ vF)
{
    __shared__ ProjShared sh;

    const int t  = threadIdx.x;
    const int n0 = blockIdx.x * 32;
    const int b  = blockIdx.y;

    {   // stage x tile transposed -> bf16 LDS
        const int ln = t & 31;
        const int cg = t >> 5;
        #pragma unroll
        for (int rr = 0; rr < 8; rr++) {
            const int c = 4*cg + 32*rr;
            const float f0 = x[((size_t)(b*C_IN + c+0))*NPT + n0 + ln];
            const float f1 = x[((size_t)(b*C_IN + c+1))*NPT + n0 + ln];
            const float f2 = x[((size_t)(b*C_IN + c+2))*NPT + n0 + ln];
            const float f3 = x[((size_t)(b*C_IN + c+3))*NPT + n0 + ln];
            ushort4 u4;
            u4.x = f2bf(f0); u4.y = f2bf(f1); u4.z = f2bf(f2); u4.w = f2bf(f3);
            *(ushort4*)&sh.x_t[ln][c] = u4;
        }
    }
    __syncthreads();

    const int w = t >> 6, l = t & 63, q = l >> 4, c16 = l & 15;

    f32x4 acc[6][2];
    #pragma unroll
    for (int ot = 0; ot < 6; ot++)
        #pragma unroll
        for (int nt = 0; nt < 2; nt++)
            acc[ot][nt] = (f32x4){0.f, 0.f, 0.f, 0.f};

    #pragma unroll
    for (int kk = 0; kk < 8; kk++) {
        const bf16x8 bf0 = *(const bf16x8*)&sh.x_t[c16     ][kk*32 + 8*q];
        const bf16x8 bf1 = *(const bf16x8*)&sh.x_t[16 + c16][kk*32 + 8*q];
        #pragma unroll
        for (int ot = 0; ot < 6; ot++) {
            const int o = 16*(4*ot + w) + c16;
            const bf16x8 af = *(const bf16x8*)&wbf[(size_t)o*C_IN + kk*32 + 8*q];
            acc[ot][0] = MFMA32(af, bf0, acc[ot][0]);
            acc[ot][1] = MFMA32(af, bf1, acc[ot][1]);
        }
    }
    __syncthreads();   // x_t dead; reuse LDS for epilogue staging

    #pragma unroll
    for (int ot = 0; ot < 6; ot++) {
        const int T  = 4*ot + w;
        const int ob = 16*T + 4*q;
        float b0 = bias[ob+0], b1 = bias[ob+1], b2 = bias[ob+2], b3 = bias[ob+3];
        #pragma unroll
        for (int nt = 0; nt < 2; nt++) {
            const f32x4 a = acc[ot][nt];
            const float v0 = a[0]+b0, v1 = a[1]+b1, v2 = a[2]+b2, v3 = a[3]+b3;
            if (ot < 2) {
                uint2 u;
                u.x = (u32)f2bf(v0) | ((u32)f2bf(v1) << 16);
                u.y = (u32)f2bf(v2) | ((u32)f2bf(v3) << 16);
                *(uint2*)&sh.ep.qk[16*nt + c16][16*T + 4*q] = u;
            } else {
                const int cb = 16*T - 128 + 4*q;
                sh.ep.vl[cb+0][16*nt + c16] = f2bf(v0);
                sh.ep.vl[cb+1][16*nt + c16] = f2bf(v1);
                sh.ep.vl[cb+2][16*nt + c16] = f2bf(v2);
                sh.ep.vl[cb+3][16*nt + c16] = f2bf(v3);
            }
        }
    }
    __syncthreads();

    {   // fragment-major global stores
        const int n    = t >> 3;
        const int c    = t & 7;
        const int g    = (n0 + n) >> 4;
        const int lane = 16*(c & 3) + (n & 15);
        const size_t dq = ((size_t)(b*256 + g))*1024 + (size_t)(c >> 2)*512 + lane*8;
        *(uint4*)&qF[dq] = *(uint4*)&sh.ep.qk[n][8*c];
        *(uint4*)&kF[dq] = *(uint4*)&sh.ep.qk[n][64 + 8*c];
        const int cg   = t >> 4, c16v = t & 15;
        const int ng   = n0 >> 5;
        u16* vdst = &vF[(((size_t)(b*16 + cg))*128 + ng)*512 + c16v*8];
        #pragma unroll
        for (int j = 0; j < 4; j++)          // lane 16j+c16v -> offset j*128
            *(uint4*)&vdst[j*128] = *(uint4*)&sh.ep.vl[t][8*j];
    }
}

// ---------------------------------------------------------------------------
// stats: no-max partial softmax sums over 1024-wide m-split via MFMA.
// 2 q-groups per wave (k fragments reused x2 -> half the k L2 traffic).
// grid (4 msplit, N/128, B), block 256.
// ---------------------------------------------------------------------------
__global__ __launch_bounds__(256, 4) void stats_kernel(
    const u16* __restrict__ qF, const u16* __restrict__ kF,
    float* __restrict__ psum)
{
    const int t = threadIdx.x;
    const int w = t >> 6, l = t & 63, q = l >> 4, c16 = l & 15;
    const int ms = blockIdx.x, nt = blockIdx.y, b = blockIdx.z;

    // wave w owns rows nt*128 + 32w .. +31  (q-groups nt*8+2w, +1)
    bf16x8 aq[2][2];
    #pragma unroll
    for (int j = 0; j < 2; j++) {
        const u16* qp = &qF[((size_t)(b*256 + nt*8 + 2*w + j))*1024 + l*8];
        aq[j][0] = *(const bf16x8*)qp;
        aq[j][1] = *(const bf16x8*)(qp + 512);
    }

    float rz[2][4] = {{0.f,0.f,0.f,0.f},{0.f,0.f,0.f,0.f}};
    const u16* kbase = &kF[((size_t)b*256)*1024 + l*8];

    for (int m0 = ms*1024; m0 < ms*1024 + 1024; m0 += 64) {
        bf16x8 k0[4], k1[4];
        #pragma unroll
        for (int mj = 0; mj < 4; mj++) {
            const u16* kp = kbase + (size_t)((m0 >> 4) + mj)*1024;
            k0[mj] = *(const bf16x8*)kp;
            k1[mj] = *(const bf16x8*)(kp + 512);
        }
        #pragma unroll
        for (int j = 0; j < 2; j++) {
            f32x4 s[4];
            #pragma unroll
            for (int mj = 0; mj < 4; mj++) {
                f32x4 a = {0.f, 0.f, 0.f, 0.f};
                a = MFMA32(aq[j][0], k0[mj], a);
                a = MFMA32(aq[j][1], k1[mj], a);
                s[mj] = a;
            }
            #pragma unroll
            for (int r = 0; r < 4; r++) {
                rz[j][r] += EXP2F(s[0][r]*L2E) + EXP2F(s[1][r]*L2E)
                          + EXP2F(s[2][r]*L2E) + EXP2F(s[3][r]*L2E);
            }
        }
    }
    #pragma unroll
    for (int j = 0; j < 2; j++)
        #pragma unroll
        for (int r = 0; r < 4; r++) {
            float Z = rz[j][r];
            #pragma unroll
            for (int d = 1; d < 16; d <<= 1) Z += __shfl_xor(Z, d, 64);
            if (c16 == 0)
                psum[((size_t)(b*4 + ms))*NPT + nt*128 + 32*w + 16*j + 4*q + r] = Z;
        }
}

// ---------------------------------------------------------------------------
// merge: Lrow[n] = log2(sum of 4 partial Z)
// ---------------------------------------------------------------------------
__global__ void merge_kernel(const float* __restrict__ psum, float* __restrict__ Lrow)
{
    const int g = blockIdx.x*256 + threadIdx.x;
    const int b = g >> 12;
    const int n = g & 4095;
    float Z = 0.f;
    #pragma unroll
    for (int s = 0; s < 4; s++) Z += psum[((size_t)(b*4+s))*NPT + n];
    Lrow[(size_t)b*NPT + n] = __log2f(Z);
}

// ---------------------------------------------------------------------------
// attn: 16 waves (1024 thr), m-tile 64, grid 256 (1 blk/CU, 4 waves/SIMD).
// Block-local n-split: sub = w>>3 processes n-half [nt*256+sub*128, +128);
// wl = w&7 owns channels 32wl..32wl+31. Per-wave per-iter work identical to
// the R6 8-wave kernel (8 QK + 32 PV MFMA, 16 exp2, 32 LDS reads) but with
// 4 waves/SIMD to fill the serial QK->exp2->barrier->PV chain, 16 iters.
// Two p tiles per buffer (one per sub-group), verified stride-17 layout.
// Partial acc reduced once at the end via a separate LDS buffer (sub1 ->
// LDS -> sub0 adds; no global split-K traffic). LDS 69.6K p + 65K red.
// ---------------------------------------------------------------------------
__global__ __launch_bounds__(1024, 4) void attn_kernel(
    const u16* __restrict__ qF, const u16* __restrict__ kF, const u16* __restrict__ vF,
    const float* __restrict__ Lrow, const float* __restrict__ gamma,
    const float* __restrict__ x, float* __restrict__ out)
{
    __shared__ uint2 p_l[2][2][2176];   // [buf][sub][unit*17+c16], 69632 B
    __shared__ float red[16640];        // [idx][wl*64+l] stride 520, 66560 B

    const int t = threadIdx.x;
    const int w = t >> 6, l = t & 63, q = l >> 4, c16 = l & 15;
    const int sub = w >> 3, wl = w & 7;

    const int id  = blockIdx.x;
    const int xcd = id & 7;                    // dispatch round-robins XCDs
    const int jb  = id >> 3;                   // 0..31
    const int b   = xcd >> 1;                  // 2 XCDs per batch -> L2 locality
    const int mt  = ((xcd & 1) << 5) | jb;     // 32 m-tiles per XCD
    const int m0  = mt * 64;

    // persistent k B-fragments: group gm = mt*4+mj
    bf16x8 kf[4][2];
    #pragma unroll
    for (int mj = 0; mj < 4; mj++) {
        const u16* kp = &kF[((size_t)(b*256 + mt*4 + mj))*1024 + l*8];
        kf[mj][0] = *(const bf16x8*)kp;
        kf[mj][1] = *(const bf16x8*)(kp + 512);
    }

    f32x4 acc[2][4];   // [cg][mj]: c = 32wl + 16cg + 4q + r (partial over sub's n)
    #pragma unroll
    for (int cg = 0; cg < 2; cg++)
        #pragma unroll
        for (int mj = 0; mj < 4; mj++)
            acc[cg][mj] = (f32x4){0.f, 0.f, 0.f, 0.f};

    // fragment-major bases
    const u16*   qbase  = &qF[((size_t)(b*256 + sub*8 + wl))*1024 + l*8];       // + nt*16384
    const u16*   vbase0 = &vF[(((size_t)(b*16 + 2*wl))*128 + 4*sub)*512 + l*8]; // + (8nt+kc)*512
    const u16*   vbase1 = vbase0 + (size_t)128*512;                             // cg+1
    const float* Lb     = &Lrow[(size_t)b*NPT + sub*128 + 16*wl + 4*q];         // + nt*256

    // LDS unit indices within own sub tile (stride-17 units of uint2)
    const int Uw  = (wl*16 + q*4)*17 + c16;                   // + mj*17
    const int Ur0 = ((q>>1)*16 + (q&1)*8)*17 + c16;           // + kc*544 + mj*17 (+68)

    int buf = 0;
    for (int nt = 0; nt < 16; nt++) {
        // q fragment for this iter's own 16 rows
        const bf16x8 qa0 = *(const bf16x8*)(qbase + (size_t)nt*16384);
        const bf16x8 qa1 = *(const bf16x8*)(qbase + (size_t)nt*16384 + 512);

        // s: wave's 16 n' rows x 64 m (K=64)
        f32x4 s[4];
        #pragma unroll
        for (int mj = 0; mj < 4; mj++) {
            f32x4 a = {0.f, 0.f, 0.f, 0.f};
            a = MFMA32(qa0, kf[mj][0], a);
            a = MFMA32(qa1, kf[mj][1], a);
            s[mj] = a;
        }
        // issue v fragments for this iter (latency covered by exp2 + barrier)
        bf16x8 va0[4], va1[4];
        #pragma unroll
        for (int kc = 0; kc < 4; kc++) {
            va0[kc] = *(const bf16x8*)(vbase0 + (size_t)(8*nt + kc)*512);
            va1[kc] = *(const bf16x8*)(vbase1 + (size_t)(8*nt + kc)*512);
        }
        const float4 Lr = *(const float4*)(Lb + nt*256);

        // p = exp2(s*L2E - Lrow), trunc-pack, store flat units
        #pragma unroll
        for (int mj = 0; mj < 4; mj++) {
            const float p0 = EXP2F(s[mj][0]*L2E - Lr.x);
            const float p1 = EXP2F(s[mj][1]*L2E - Lr.y);
            const float p2 = EXP2F(s[mj][2]*L2E - Lr.z);
            const float p3 = EXP2F(s[mj][3]*L2E - Lr.w);
            uint2 u;
            u.x = pack_trunc(p0, p1);
            u.y = pack_trunc(p2, p3);
            p_l[buf][sub][Uw + mj*17] = u;
        }
        __syncthreads();

        // PV over own sub tile: K=128 as 4 chunks of 32
        const uint2* tp = p_l[buf][sub];
        __builtin_amdgcn_s_setprio(1);
        #pragma unroll
        for (int mj = 0; mj < 4; mj++) {
            #pragma unroll
            for (int kc = 0; kc < 4; kc++) {
                const uint2 u0 = tp[Ur0 + kc*544 + mj*17];
                const uint2 u1 = tp[Ur0 + kc*544 + mj*17 + 68];
                uint4 f = make_uint4(u0.x, u0.y, u1.x, u1.y);
                const bf16x8 pf = *(bf16x8*)&f;
                acc[0][mj] = MFMA32(va0[kc], pf, acc[0][mj]);
                acc[1][mj] = MFMA32(va1[kc], pf, acc[1][mj]);
            }
        }
        __builtin_amdgcn_s_setprio(0);
        buf ^= 1;
    }

    // cross-sub reduction of partial acc, then epilogue by sub0
    if (sub == 1) {
        #pragma unroll
        for (int cg = 0; cg < 2; cg++)
            #pragma unroll
            for (int mj = 0; mj < 4; mj++)
                #pragma unroll
                for (int r = 0; r < 4; r++)
                    red[((cg*4 + mj)*4 + r)*520 + wl*64 + l] = acc[cg][mj][r];
    }
    __syncthreads();
    if (sub == 0) {
        const float g = gamma[0];
        #pragma unroll
        for (int cg = 0; cg < 2; cg++)
            #pragma unroll
            for (int mj = 0; mj < 4; mj++)
                #pragma unroll
                for (int r = 0; r < 4; r++) {
                    const float v = acc[cg][mj][r]
                                  + red[((cg*4 + mj)*4 + r)*520 + wl*64 + l];
                    const size_t o = ((size_t)(b*C_IN + 32*wl + 16*cg + 4*q + r))*NPT
                                   + m0 + 16*mj + c16;
                    out[o] = g*v + x[o];
                }
    }
}

// ---------------------------------------------------------------------------
extern "C" void kernel_launch(void* const* d_in, const int* in_sizes, int n_in,
                              void* d_out, int out_size, void* d_ws, size_t ws_size,
                              hipStream_t stream)
{
    const float* x     = (const float*)d_in[0];
    const float* wq    = (const float*)d_in[1];
    const float* bq    = (const float*)d_in[2];
    const float* wk    = (const float*)d_in[3];
    const float* bk    = (const float*)d_in[4];
    const float* wv    = (const float*)d_in[5];
    const float* bv    = (const float*)d_in[6];
    const float* gamma = (const float*)d_in[7];
    float* out = (float*)d_out;

    u16* qF  = (u16*)d_ws;                              // 2 MB
    u16* kF  = qF  + (size_t)NB*NPT*CQD;                // 2 MB
    u16* vF  = kF  + (size_t)NB*NPT*CQD;                // 8 MB
    u16* wbf = vF  + (size_t)NB*C_IN*NPT;               // 192 KB
    float* fp    = (float*)(wbf + 384*256);
    float* bias  = fp;                                  // 384
    float* psum  = bias + 384;                          // 64 KB
    float* Lrow  = psum + (size_t)NB*4*NPT;             // 64 KB

    prep_kernel<<<dim3(386), 256, 0, stream>>>(wq, bq, wk, bk, wv, bv, wbf, bias);
    proj_kernel<<<dim3(NPT/32, NB), 256, 0, stream>>>(x, wbf, bias, qF, kF, vF);
    stats_kernel<<<dim3(4, NPT/128, NB), 256, 0, stream>>>(qF, kF, psum);
    merge_kernel<<<dim3(64), 256, 0, stream>>>(psum, Lrow);
    attn_kernel<<<dim3(256), 1024, 0, stream>>>(qF, kF, vF, Lrow, gamma, x, out);
}

// Round 8
// 163.639 us; speedup vs baseline: 1.8991x; 1.0182x over previous
//
#include <hip/hip_runtime.h>

#define NB   4
#define C_IN 256
#define CQD  64
#define NPT  4096
#define L2E  1.44269504088896f

typedef __attribute__((ext_vector_type(8))) short bf16x8;
typedef __attribute__((ext_vector_type(4))) float f32x4;
typedef unsigned short u16;
typedef unsigned int   u32;

#define EXP2F(x)      __builtin_amdgcn_exp2f(x)
#define MFMA32(A,B,C) __builtin_amdgcn_mfma_f32_16x16x32_bf16(A,B,C,0,0,0)

__device__ __forceinline__ u16 f2bf(float f) {          // RNE (cold paths)
    u32 u = __float_as_uint(f);
    u += 0x7fff + ((u >> 16) & 1);
    return (u16)(u >> 16);
}
// one v_perm: (bf16_trunc(hi)<<16) | bf16_trunc(lo)
__device__ __forceinline__ u32 pack_trunc(float lo, float hi) {
    return __builtin_amdgcn_perm(__float_as_uint(hi), __float_as_uint(lo), 0x07060302u);
}

// ---------------------------------------------------------------------------
// Fragment-major layouts (1 request per wave fragment load):
//   qF/kF: [b][g][half][lane][8] u16, g = seq/16, half = o-chunk/4,
//          lane = 16*q + c16 holds (row 16g+c16, o elems 8*(q+4*half)..+7).
//   vF:    [b][cg][ng][lane][8] u16, cg = c/16, ng = n/32,
//          lane = 16*q + c16 holds (row 16cg+c16, n elems 32ng+8q..+7).
// ---------------------------------------------------------------------------

// ---------------------------------------------------------------------------
// prep: pack wq|wk|wv into bf16 wbf[384][256], biases into bias[384]
// ---------------------------------------------------------------------------
__global__ void prep_kernel(
    const float* __restrict__ wq, const float* __restrict__ bq,
    const float* __restrict__ wk, const float* __restrict__ bk,
    const float* __restrict__ wv, const float* __restrict__ bv,
    u16* __restrict__ wbf, float* __restrict__ bias)
{
    const int gid = blockIdx.x*256 + threadIdx.x;
    if (gid < 384*256) {
        const int r = gid >> 8, c = gid & 255;
        const float v = (r < 64) ? wq[r*256 + c]
                      : (r < 128) ? wk[(r-64)*256 + c]
                                  : wv[(r-128)*256 + c];
        wbf[gid] = f2bf(v);
    } else if (gid < 384*256 + 384) {
        const int r = gid - 384*256;
        bias[r] = (r < 64) ? bq[r] : (r < 128) ? bk[r-64] : bv[r-128];
    }
}

// ---------------------------------------------------------------------------
// proj: MFMA pointwise projections, x read ONCE. Wave w owns tiles T=4*ot+w.
// grid (N/32, B), block 256. Epilogue stores in fragment-major layouts.
// ---------------------------------------------------------------------------
union ProjShared {
    u16 x_t[32][264];                            // [n][c] bf16, stride 528B
    struct { u16 qk[32][136]; u16 vl[256][40]; } ep;
};

__global__ __launch_bounds__(256) void proj_kernel(
    const float* __restrict__ x, const u16* __restrict__ wbf,
    const float* __restrict__ bias,
    u16* __restrict__ qF, u16* __restrict__ kF, u16* __restrict__ vF)
{
    __shared__ ProjShared sh;

    const int t  = threadIdx.x;
    const int n0 = blockIdx.x * 32;
    const int b  = blockIdx.y;

    {   // stage x tile transposed -> bf16 LDS
        const int ln = t & 31;
        const int cg = t >> 5;
        #pragma unroll
        for (int rr = 0; rr < 8; rr++) {
            const int c = 4*cg + 32*rr;
            const float f0 = x[((size_t)(b*C_IN + c+0))*NPT + n0 + ln];
            const float f1 = x[((size_t)(b*C_IN + c+1))*NPT + n0 + ln];
            const float f2 = x[((size_t)(b*C_IN + c+2))*NPT + n0 + ln];
            const float f3 = x[((size_t)(b*C_IN + c+3))*NPT + n0 + ln];
            ushort4 u4;
            u4.x = f2bf(f0); u4.y = f2bf(f1); u4.z = f2bf(f2); u4.w = f2bf(f3);
            *(ushort4*)&sh.x_t[ln][c] = u4;
        }
    }
    __syncthreads();

    const int w = t >> 6, l = t & 63, q = l >> 4, c16 = l & 15;

    f32x4 acc[6][2];
    #pragma unroll
    for (int ot = 0; ot < 6; ot++)
        #pragma unroll
        for (int nt = 0; nt < 2; nt++)
            acc[ot][nt] = (f32x4){0.f, 0.f, 0.f, 0.f};

    #pragma unroll
    for (int kk = 0; kk < 8; kk++) {
        const bf16x8 bf0 = *(const bf16x8*)&sh.x_t[c16     ][kk*32 + 8*q];
        const bf16x8 bf1 = *(const bf16x8*)&sh.x_t[16 + c16][kk*32 + 8*q];
        #pragma unroll
        for (int ot = 0; ot < 6; ot++) {
            const int o = 16*(4*ot + w) + c16;
            const bf16x8 af = *(const bf16x8*)&wbf[(size_t)o*C_IN + kk*32 + 8*q];
            acc[ot][0] = MFMA32(af, bf0, acc[ot][0]);
            acc[ot][1] = MFMA32(af, bf1, acc[ot][1]);
        }
    }
    __syncthreads();   // x_t dead; reuse LDS for epilogue staging

    #pragma unroll
    for (int ot = 0; ot < 6; ot++) {
        const int T  = 4*ot + w;
        const int ob = 16*T + 4*q;
        float b0 = bias[ob+0], b1 = bias[ob+1], b2 = bias[ob+2], b3 = bias[ob+3];
        #pragma unroll
        for (int nt = 0; nt < 2; nt++) {
            const f32x4 a = acc[ot][nt];
            const float v0 = a[0]+b0, v1 = a[1]+b1, v2 = a[2]+b2, v3 = a[3]+b3;
            if (ot < 2) {
                uint2 u;
                u.x = (u32)f2bf(v0) | ((u32)f2bf(v1) << 16);
                u.y = (u32)f2bf(v2) | ((u32)f2bf(v3) << 16);
                *(uint2*)&sh.ep.qk[16*nt + c16][16*T + 4*q] = u;
            } else {
                const int cb = 16*T - 128 + 4*q;
                sh.ep.vl[cb+0][16*nt + c16] = f2bf(v0);
                sh.ep.vl[cb+1][16*nt + c16] = f2bf(v1);
                sh.ep.vl[cb+2][16*nt + c16] = f2bf(v2);
                sh.ep.vl[cb+3][16*nt + c16] = f2bf(v3);
            }
        }
    }
    __syncthreads();

    {   // fragment-major global stores
        const int n    = t >> 3;
        const int c    = t & 7;
        const int g    = (n0 + n) >> 4;
        const int lane = 16*(c & 3) + (n & 15);
        const size_t dq = ((size_t)(b*256 + g))*1024 + (size_t)(c >> 2)*512 + lane*8;
        *(uint4*)&qF[dq] = *(uint4*)&sh.ep.qk[n][8*c];
        *(uint4*)&kF[dq] = *(uint4*)&sh.ep.qk[n][64 + 8*c];
        const int cg   = t >> 4, c16v = t & 15;
        const int ng   = n0 >> 5;
        u16* vdst = &vF[(((size_t)(b*16 + cg))*128 + ng)*512 + c16v*8];
        #pragma unroll
        for (int j = 0; j < 4; j++)          // lane 16j+c16v -> offset j*128
            *(uint4*)&vdst[j*128] = *(uint4*)&sh.ep.vl[t][8*j];
    }
}

// ---------------------------------------------------------------------------
// stats: no-max partial softmax sums over 1024-wide m-split via MFMA.
// 2 q-groups per wave (k fragments reused x2 -> half the k L2 traffic).
// grid (4 msplit, N/128, B), block 256.
// ---------------------------------------------------------------------------
__global__ __launch_bounds__(256, 4) void stats_kernel(
    const u16* __restrict__ qF, const u16* __restrict__ kF,
    float* __restrict__ psum)
{
    const int t = threadIdx.x;
    const int w = t >> 6, l = t & 63, q = l >> 4, c16 = l & 15;
    const int ms = blockIdx.x, nt = blockIdx.y, b = blockIdx.z;

    // wave w owns rows nt*128 + 32w .. +31  (q-groups nt*8+2w, +1)
    bf16x8 aq[2][2];
    #pragma unroll
    for (int j = 0; j < 2; j++) {
        const u16* qp = &qF[((size_t)(b*256 + nt*8 + 2*w + j))*1024 + l*8];
        aq[j][0] = *(const bf16x8*)qp;
        aq[j][1] = *(const bf16x8*)(qp + 512);
    }

    float rz[2][4] = {{0.f,0.f,0.f,0.f},{0.f,0.f,0.f,0.f}};
    const u16* kbase = &kF[((size_t)b*256)*1024 + l*8];

    for (int m0 = ms*1024; m0 < ms*1024 + 1024; m0 += 64) {
        bf16x8 k0[4], k1[4];
        #pragma unroll
        for (int mj = 0; mj < 4; mj++) {
            const u16* kp = kbase + (size_t)((m0 >> 4) + mj)*1024;
            k0[mj] = *(const bf16x8*)kp;
            k1[mj] = *(const bf16x8*)(kp + 512);
        }
        #pragma unroll
        for (int j = 0; j < 2; j++) {
            f32x4 s[4];
            #pragma unroll
            for (int mj = 0; mj < 4; mj++) {
                f32x4 a = {0.f, 0.f, 0.f, 0.f};
                a = MFMA32(aq[j][0], k0[mj], a);
                a = MFMA32(aq[j][1], k1[mj], a);
                s[mj] = a;
            }
            #pragma unroll
            for (int r = 0; r < 4; r++) {
                rz[j][r] += EXP2F(s[0][r]*L2E) + EXP2F(s[1][r]*L2E)
                          + EXP2F(s[2][r]*L2E) + EXP2F(s[3][r]*L2E);
            }
        }
    }
    #pragma unroll
    for (int j = 0; j < 2; j++)
        #pragma unroll
        for (int r = 0; r < 4; r++) {
            float Z = rz[j][r];
            #pragma unroll
            for (int d = 1; d < 16; d <<= 1) Z += __shfl_xor(Z, d, 64);
            if (c16 == 0)
                psum[((size_t)(b*4 + ms))*NPT + nt*128 + 32*w + 16*j + 4*q + r] = Z;
        }
}

// ---------------------------------------------------------------------------
// merge: Lrow[n] = log2(sum of 4 partial Z)
// ---------------------------------------------------------------------------
__global__ void merge_kernel(const float* __restrict__ psum, float* __restrict__ Lrow)
{
    const int g = blockIdx.x*256 + threadIdx.x;
    const int b = g >> 12;
    const int n = g & 4095;
    float Z = 0.f;
    #pragma unroll
    for (int s = 0; s < 4; s++) Z += psum[((size_t)(b*4+s))*NPT + n];
    Lrow[(size_t)b*NPT + n] = __log2f(Z);
}

// ---------------------------------------------------------------------------
// attn: MERGED-REGION schedule. 8 waves (512 thr), m-tile 64, grid 256
// (1 blk/CU, 2 waves/SIMD — MFMA pipe is per-SIMD and one wave's 40
// back-to-back MFMAs saturate it IF they're schedulable together).
// R7 lesson: occupancy 19->37% changed nothing; the binder is barrier
// phase-alignment — QK/exp and PV sat in separate scheduling regions so
// MFMA drained during VALU phase and vice versa.
// New loop body = ONE region: [BARRIER; QK_{nt+1}; PV_nt; prefetch
// q/v/L; exp_{nt+1}; write p[buf^1]]. QK_{nt+1} and PV_nt are independent
// MFMAs; exp slots into their shadow. Same 1 barrier/iter + p dbuf
// invariants (write buf^1 / read buf separated by next barrier). Last
// iter peeled -> branch-free body. MFMA floor ~21 us.
// p LDS layout (verified): unit U(w,q,mj) = (w*16+q*4+mj)*17 + c16.
// ---------------------------------------------------------------------------
__global__ __launch_bounds__(512, 2) void attn_kernel(
    const u16* __restrict__ qF, const u16* __restrict__ kF, const u16* __restrict__ vF,
    const float* __restrict__ Lrow, const float* __restrict__ gamma,
    const float* __restrict__ x, float* __restrict__ out)
{
    __shared__ uint2 p_l[2][2176];   // 2 x 17408 B

    const int t = threadIdx.x;
    const int w = t >> 6, l = t & 63, q = l >> 4, c16 = l & 15;

    const int id  = blockIdx.x;
    const int xcd = id & 7;                    // dispatch round-robins XCDs
    const int jb  = id >> 3;                   // 0..31
    const int b   = xcd >> 1;                  // 2 XCDs per batch -> L2 locality
    const int mt  = ((xcd & 1) << 5) | jb;     // 32 m-tiles per XCD
    const int m0  = mt * 64;

    // persistent k B-fragments: group gm = mt*4+mj
    bf16x8 kf[4][2];
    #pragma unroll
    for (int mj = 0; mj < 4; mj++) {
        const u16* kp = &kF[((size_t)(b*256 + mt*4 + mj))*1024 + l*8];
        kf[mj][0] = *(const bf16x8*)kp;
        kf[mj][1] = *(const bf16x8*)(kp + 512);
    }

    f32x4 acc[2][4];   // [cg][mj]: c = 32w + 16cg + 4q + r, m = m0 + 16mj + c16
    #pragma unroll
    for (int cg = 0; cg < 2; cg++)
        #pragma unroll
        for (int mj = 0; mj < 4; mj++)
            acc[cg][mj] = (f32x4){0.f, 0.f, 0.f, 0.f};

    // fragment-major bases (all lane-contiguous)
    const u16*   qbase  = &qF[((size_t)(b*256 + w))*1024 + l*8];        // + nt*8192
    const u16*   vbase0 = &vF[(((size_t)(b*16 + 2*w))*128)*512 + l*8];  // + (nt*4+kc)*512
    const u16*   vbase1 = vbase0 + (size_t)128*512;                     // cg+1
    const float* Lb     = &Lrow[(size_t)b*NPT + 16*w + 4*q];

    // LDS unit indices (stride-17 units of uint2)
    const int Uw  = (w*16 + q*4)*17 + c16;                    // + mj*17
    const int Ur0 = ((q>>1)*16 + (q&1)*8)*17 + c16;           // + kc*544 + mj*17 (+68)

    // ---- prologue: tile 0 scores -> p[0]; stage tile-0 v, tile-1 q/L ----
    bf16x8 qa0 = *(const bf16x8*)qbase;
    bf16x8 qa1 = *(const bf16x8*)(qbase + 512);
    bf16x8 vac0[4], vac1[4];
    #pragma unroll
    for (int kc = 0; kc < 4; kc++) {
        vac0[kc] = *(const bf16x8*)(vbase0 + (size_t)kc*512);
        vac1[kc] = *(const bf16x8*)(vbase1 + (size_t)kc*512);
    }
    float4 Lrc = *(const float4*)Lb;
    {
        f32x4 s[4];
        #pragma unroll
        for (int mj = 0; mj < 4; mj++) {
            f32x4 a = {0.f, 0.f, 0.f, 0.f};
            a = MFMA32(qa0, kf[mj][0], a);
            a = MFMA32(qa1, kf[mj][1], a);
            s[mj] = a;
        }
        #pragma unroll
        for (int mj = 0; mj < 4; mj++) {
            const float p0 = EXP2F(s[mj][0]*L2E - Lrc.x);
            const float p1 = EXP2F(s[mj][1]*L2E - Lrc.y);
            const float p2 = EXP2F(s[mj][2]*L2E - Lrc.z);
            const float p3 = EXP2F(s[mj][3]*L2E - Lrc.w);
            uint2 u;
            u.x = pack_trunc(p0, p1);
            u.y = pack_trunc(p2, p3);
            p_l[0][Uw + mj*17] = u;
        }
    }
    qa0 = *(const bf16x8*)(qbase + 8192);        // tile 1
    qa1 = *(const bf16x8*)(qbase + 8192 + 512);
    Lrc = *(const float4*)(Lb + 128);            // tile 1

    int buf = 0;
    for (int nt = 0; nt < 31; nt++) {
        __syncthreads();
        // --- single merged region: QK_{nt+1} || PV_nt || exp_{nt+1} ---
        f32x4 s[4];
        #pragma unroll
        for (int mj = 0; mj < 4; mj++) {
            f32x4 a = {0.f, 0.f, 0.f, 0.f};
            a = MFMA32(qa0, kf[mj][0], a);
            a = MFMA32(qa1, kf[mj][1], a);
            s[mj] = a;
        }
        #pragma unroll
        for (int mj = 0; mj < 4; mj++) {
            #pragma unroll
            for (int kc = 0; kc < 4; kc++) {
                const uint2 u0 = p_l[buf][Ur0 + kc*544 + mj*17];
                const uint2 u1 = p_l[buf][Ur0 + kc*544 + mj*17 + 68];
                uint4 f = make_uint4(u0.x, u0.y, u1.x, u1.y);
                const bf16x8 pf = *(bf16x8*)&f;
                acc[0][mj] = MFMA32(vac0[kc], pf, acc[0][mj]);
                acc[1][mj] = MFMA32(vac1[kc], pf, acc[1][mj]);
            }
        }
        // prefetch: q tile nt+2 (clamped), v tile nt+1, L tile nt+2 (clamped)
        const int n2 = (nt < 30) ? nt + 2 : 31;
        qa0 = *(const bf16x8*)(qbase + (size_t)n2*8192);
        qa1 = *(const bf16x8*)(qbase + (size_t)n2*8192 + 512);
        bf16x8 van0[4], van1[4];
        #pragma unroll
        for (int kc = 0; kc < 4; kc++) {
            van0[kc] = *(const bf16x8*)(vbase0 + (size_t)((nt+1)*4 + kc)*512);
            van1[kc] = *(const bf16x8*)(vbase1 + (size_t)((nt+1)*4 + kc)*512);
        }
        const float4 Lrn = *(const float4*)(Lb + (size_t)n2*128);

        // exp + write p[buf^1] for tile nt+1 (uses Lrc = L tile nt+1)
        #pragma unroll
        for (int mj = 0; mj < 4; mj++) {
            const float p0 = EXP2F(s[mj][0]*L2E - Lrc.x);
            const float p1 = EXP2F(s[mj][1]*L2E - Lrc.y);
            const float p2 = EXP2F(s[mj][2]*L2E - Lrc.z);
            const float p3 = EXP2F(s[mj][3]*L2E - Lrc.w);
            uint2 u;
            u.x = pack_trunc(p0, p1);
            u.y = pack_trunc(p2, p3);
            p_l[buf^1][Uw + mj*17] = u;
        }
        // rotate prefetch buffers (compile-time indices)
        #pragma unroll
        for (int kc = 0; kc < 4; kc++) {
            vac0[kc] = van0[kc];
            vac1[kc] = van1[kc];
        }
        Lrc = Lrn;
        buf ^= 1;
    }
    // peeled final tile (31): PV only
    __syncthreads();
    #pragma unroll
    for (int mj = 0; mj < 4; mj++) {
        #pragma unroll
        for (int kc = 0; kc < 4; kc++) {
            const uint2 u0 = p_l[buf][Ur0 + kc*544 + mj*17];
            const uint2 u1 = p_l[buf][Ur0 + kc*544 + mj*17 + 68];
            uint4 f = make_uint4(u0.x, u0.y, u1.x, u1.y);
            const bf16x8 pf = *(bf16x8*)&f;
            acc[0][mj] = MFMA32(vac0[kc], pf, acc[0][mj]);
            acc[1][mj] = MFMA32(vac1[kc], pf, acc[1][mj]);
        }
    }

    const float g = gamma[0];
    #pragma unroll
    for (int cg = 0; cg < 2; cg++)
        #pragma unroll
        for (int mj = 0; mj < 4; mj++)
            #pragma unroll
            for (int r = 0; r < 4; r++) {
                const size_t o = ((size_t)(b*C_IN + 32*w + 16*cg + 4*q + r))*NPT
                               + m0 + 16*mj + c16;
                out[o] = g*acc[cg][mj][r] + x[o];
            }
}

// ---------------------------------------------------------------------------
extern "C" void kernel_launch(void* const* d_in, const int* in_sizes, int n_in,
                              void* d_out, int out_size, void* d_ws, size_t ws_size,
                              hipStream_t stream)
{
    const float* x     = (const float*)d_in[0];
    const float* wq    = (const float*)d_in[1];
    const float* bq    = (const float*)d_in[2];
    const float* wk    = (const float*)d_in[3];
    const float* bk    = (const float*)d_in[4];
    const float* wv    = (const float*)d_in[5];
    const float* bv    = (const float*)d_in[6];
    const float* gamma = (const float*)d_in[7];
    float* out = (float*)d_out;

    u16* qF  = (u16*)d_ws;                              // 2 MB
    u16* kF  = qF  + (size_t)NB*NPT*CQD;                // 2 MB
    u16* vF  = kF  + (size_t)NB*NPT*CQD;                // 8 MB
    u16* wbf = vF  + (size_t)NB*C_IN*NPT;               // 192 KB
    float* fp    = (float*)(wbf + 384*256);
    float* bias  = fp;                                  // 384
    float* psum  = bias + 384;                          // 64 KB
    float* Lrow  = psum + (size_t)NB*4*NPT;             // 64 KB

    prep_kernel<<<dim3(386), 256, 0, stream>>>(wq, bq, wk, bk, wv, bv, wbf, bias);
    proj_kernel<<<dim3(NPT/32, NB), 256, 0, stream>>>(x, wbf, bias, qF, kF, vF);
    stats_kernel<<<dim3(4, NPT/128, NB), 256, 0, stream>>>(qF, kF, psum);
    merge_kernel<<<dim3(64), 256, 0, stream>>>(psum, Lrow);
    attn_kernel<<<dim3(256), 512, 0, stream>>>(qF, kF, vF, Lrow, gamma, x, out);
}

// Round 9
// 144.683 us; speedup vs baseline: 2.1479x; 1.1310x over previous
//
#include <hip/hip_runtime.h>

#define NB   4
#define C_IN 256
#define CQD  64
#define NPT  4096
#define L2E  1.44269504088896f

typedef __attribute__((ext_vector_type(8))) short bf16x8;
typedef __attribute__((ext_vector_type(4))) float f32x4;
typedef unsigned short u16;
typedef unsigned int   u32;

#define EXP2F(x)      __builtin_amdgcn_exp2f(x)
#define MFMA32(A,B,C) __builtin_amdgcn_mfma_f32_16x16x32_bf16(A,B,C,0,0,0)

__device__ __forceinline__ u16 f2bf(float f) {          // RNE (cold paths)
    u32 u = __float_as_uint(f);
    u += 0x7fff + ((u >> 16) & 1);
    return (u16)(u >> 16);
}
// one v_perm: (bf16_trunc(hi)<<16) | bf16_trunc(lo)
__device__ __forceinline__ u32 pack_trunc(float lo, float hi) {
    return __builtin_amdgcn_perm(__float_as_uint(hi), __float_as_uint(lo), 0x07060302u);
}

// ---------------------------------------------------------------------------
// Fragment-major layouts (1 request per wave fragment load):
//   qF/kF: [b][g][half][lane][8] u16, g = seq/16, half = o-chunk/4,
//          lane = 16*q + c16 holds (row 16g+c16, o elems 8*(q+4*half)..+7).
//   vF:    [b][cg][pg][lane][8] u16, cg = c/16, pg = pos/32,
//          lane = 16*q + c16 holds (row 16cg+c16, pos elems 32pg+8q..+7).
// ---------------------------------------------------------------------------

// ---------------------------------------------------------------------------
// prep: pack wq|wk|wv into bf16 wbf[384][256], biases into bias[384]
// ---------------------------------------------------------------------------
__global__ void prep_kernel(
    const float* __restrict__ wq, const float* __restrict__ bq,
    const float* __restrict__ wk, const float* __restrict__ bk,
    const float* __restrict__ wv, const float* __restrict__ bv,
    u16* __restrict__ wbf, float* __restrict__ bias)
{
    const int gid = blockIdx.x*256 + threadIdx.x;
    if (gid < 384*256) {
        const int r = gid >> 8, c = gid & 255;
        const float v = (r < 64) ? wq[r*256 + c]
                      : (r < 128) ? wk[(r-64)*256 + c]
                                  : wv[(r-128)*256 + c];
        wbf[gid] = f2bf(v);
    } else if (gid < 384*256 + 384) {
        const int r = gid - 384*256;
        bias[r] = (r < 64) ? bq[r] : (r < 128) ? bk[r-64] : bv[r-128];
    }
}

// ---------------------------------------------------------------------------
// proj: MFMA pointwise projections, x read ONCE. Wave w owns tiles T=4*ot+w.
// grid (N/32, B), block 256. Epilogue stores in fragment-major layouts.
// ---------------------------------------------------------------------------
union ProjShared {
    u16 x_t[32][264];                            // [n][c] bf16, stride 528B
    struct { u16 qk[32][136]; u16 vl[256][40]; } ep;
};

__global__ __launch_bounds__(256) void proj_kernel(
    const float* __restrict__ x, const u16* __restrict__ wbf,
    const float* __restrict__ bias,
    u16* __restrict__ qF, u16* __restrict__ kF, u16* __restrict__ vF)
{
    __shared__ ProjShared sh;

    const int t  = threadIdx.x;
    const int n0 = blockIdx.x * 32;
    const int b  = blockIdx.y;

    {   // stage x tile transposed -> bf16 LDS
        const int ln = t & 31;
        const int cg = t >> 5;
        #pragma unroll
        for (int rr = 0; rr < 8; rr++) {
            const int c = 4*cg + 32*rr;
            const float f0 = x[((size_t)(b*C_IN + c+0))*NPT + n0 + ln];
            const float f1 = x[((size_t)(b*C_IN + c+1))*NPT + n0 + ln];
            const float f2 = x[((size_t)(b*C_IN + c+2))*NPT + n0 + ln];
            const float f3 = x[((size_t)(b*C_IN + c+3))*NPT + n0 + ln];
            ushort4 u4;
            u4.x = f2bf(f0); u4.y = f2bf(f1); u4.z = f2bf(f2); u4.w = f2bf(f3);
            *(ushort4*)&sh.x_t[ln][c] = u4;
        }
    }
    __syncthreads();

    const int w = t >> 6, l = t & 63, q = l >> 4, c16 = l & 15;

    f32x4 acc[6][2];
    #pragma unroll
    for (int ot = 0; ot < 6; ot++)
        #pragma unroll
        for (int nt = 0; nt < 2; nt++)
            acc[ot][nt] = (f32x4){0.f, 0.f, 0.f, 0.f};

    #pragma unroll
    for (int kk = 0; kk < 8; kk++) {
        const bf16x8 bf0 = *(const bf16x8*)&sh.x_t[c16     ][kk*32 + 8*q];
        const bf16x8 bf1 = *(const bf16x8*)&sh.x_t[16 + c16][kk*32 + 8*q];
        #pragma unroll
        for (int ot = 0; ot < 6; ot++) {
            const int o = 16*(4*ot + w) + c16;
            const bf16x8 af = *(const bf16x8*)&wbf[(size_t)o*C_IN + kk*32 + 8*q];
            acc[ot][0] = MFMA32(af, bf0, acc[ot][0]);
            acc[ot][1] = MFMA32(af, bf1, acc[ot][1]);
        }
    }
    __syncthreads();   // x_t dead; reuse LDS for epilogue staging

    #pragma unroll
    for (int ot = 0; ot < 6; ot++) {
        const int T  = 4*ot + w;
        const int ob = 16*T + 4*q;
        float b0 = bias[ob+0], b1 = bias[ob+1], b2 = bias[ob+2], b3 = bias[ob+3];
        #pragma unroll
        for (int nt = 0; nt < 2; nt++) {
            const f32x4 a = acc[ot][nt];
            const float v0 = a[0]+b0, v1 = a[1]+b1, v2 = a[2]+b2, v3 = a[3]+b3;
            if (ot < 2) {
                uint2 u;
                u.x = (u32)f2bf(v0) | ((u32)f2bf(v1) << 16);
                u.y = (u32)f2bf(v2) | ((u32)f2bf(v3) << 16);
                *(uint2*)&sh.ep.qk[16*nt + c16][16*T + 4*q] = u;
            } else {
                const int cb = 16*T - 128 + 4*q;
                sh.ep.vl[cb+0][16*nt + c16] = f2bf(v0);
                sh.ep.vl[cb+1][16*nt + c16] = f2bf(v1);
                sh.ep.vl[cb+2][16*nt + c16] = f2bf(v2);
                sh.ep.vl[cb+3][16*nt + c16] = f2bf(v3);
            }
        }
    }
    __syncthreads();

    {   // fragment-major global stores
        const int n    = t >> 3;
        const int c    = t & 7;
        const int g    = (n0 + n) >> 4;
        const int lane = 16*(c & 3) + (n & 15);
        const size_t dq = ((size_t)(b*256 + g))*1024 + (size_t)(c >> 2)*512 + lane*8;
        *(uint4*)&qF[dq] = *(uint4*)&sh.ep.qk[n][8*c];
        *(uint4*)&kF[dq] = *(uint4*)&sh.ep.qk[n][64 + 8*c];
        const int cg   = t >> 4, c16v = t & 15;
        const int pg   = n0 >> 5;
        u16* vdst = &vF[(((size_t)(b*16 + cg))*128 + pg)*512 + c16v*8];
        #pragma unroll
        for (int j = 0; j < 4; j++)          // lane 16j+c16v -> offset j*128
            *(uint4*)&vdst[j*128] = *(uint4*)&sh.ep.vl[t][8*j];
    }
}

// ---------------------------------------------------------------------------
// attn (FUSED softmax): block owns n-tile 64 (softmax ROW index) and
// iterates ALL m -> full denominator z[n] accumulates in-block. Unnormalized
// p~ = exp2(s*L2E) (no-max safe: stats already summed raw exp(s) in f32;
// s ~ N(0,2.7^2), max ~15 -> e^15 ~ 3e6, inside bf16/f32 range). Normalize
// once at the end: out = gamma*(acc/z) + x. stats/merge kernels DELETED.
// Exact n<->m mirror of the verified R8 merged-region body: persistent q
// fragments (was k), streamed k (was q), v streams over iterated position
// (unchanged). One barrier/iter, p dbuf, merged region
// [BARRIER; QK_{t+1}; PV_t; prefetch; exp+z_{t+1}; write p[buf^1]].
// End: z shfl-reduce over q, zl[8][68] LDS reduce over waves, 4 rcp.
// p LDS layout (verified): unit U(w,q,nj) = (w*16+q*4+nj)*17 + c16.
// grid 256 = 4b x 64 n-tiles XCD-grouped, block 512, 1 blk/CU.
// ---------------------------------------------------------------------------
__global__ __launch_bounds__(512, 2) void attn_kernel(
    const u16* __restrict__ qF, const u16* __restrict__ kF, const u16* __restrict__ vF,
    const float* __restrict__ gamma,
    const float* __restrict__ x, float* __restrict__ out)
{
    __shared__ uint2 p_l[2][2176];   // 2 x 17408 B
    __shared__ float zl[8][68];      // per-wave z partials (padded)

    const int t = threadIdx.x;
    const int w = t >> 6, l = t & 63, q = l >> 4, c16 = l & 15;

    const int id  = blockIdx.x;
    const int xcd = id & 7;                    // dispatch round-robins XCDs
    const int jb  = id >> 3;                   // 0..31
    const int b   = xcd >> 1;                  // 2 XCDs per batch -> L2 locality
    const int ntt = ((xcd & 1) << 5) | jb;     // 32 n-tiles per XCD
    const int n0  = ntt * 64;

    // persistent q B-fragments: group gn = ntt*4 + nj (block's 64 n-rows)
    bf16x8 qf[4][2];
    #pragma unroll
    for (int nj = 0; nj < 4; nj++) {
        const u16* qp = &qF[((size_t)(b*256 + ntt*4 + nj))*1024 + l*8];
        qf[nj][0] = *(const bf16x8*)qp;
        qf[nj][1] = *(const bf16x8*)(qp + 512);
    }

    f32x4 acc[2][4];   // [cg][nj]: c = 32w + 16cg + 4q + r, n = n0 + 16nj + c16
    #pragma unroll
    for (int cg = 0; cg < 2; cg++)
        #pragma unroll
        for (int nj = 0; nj < 4; nj++)
            acc[cg][nj] = (f32x4){0.f, 0.f, 0.f, 0.f};

    float zacc[4] = {0.f, 0.f, 0.f, 0.f};   // [nj]: n = n0 + 16nj + c16 partials

    // fragment-major bases (all lane-contiguous)
    const u16* kbase  = &kF[((size_t)(b*256 + w))*1024 + l*8];        // + mt*8192
    const u16* vbase0 = &vF[(((size_t)(b*16 + 2*w))*128)*512 + l*8];  // + (mt*4+kc)*512
    const u16* vbase1 = vbase0 + (size_t)128*512;                     // cg+1

    // LDS unit indices (stride-17 units of uint2)
    const int Uw  = (w*16 + q*4)*17 + c16;                    // + nj*17
    const int Ur0 = ((q>>1)*16 + (q&1)*8)*17 + c16;           // + kc*544 + nj*17 (+68)

    // ---- prologue: m-tile 0 scores -> p[0]; stage tile-0 v, tile-1 k ----
    bf16x8 ka0 = *(const bf16x8*)kbase;
    bf16x8 ka1 = *(const bf16x8*)(kbase + 512);
    bf16x8 vac0[4], vac1[4];
    #pragma unroll
    for (int kc = 0; kc < 4; kc++) {
        vac0[kc] = *(const bf16x8*)(vbase0 + (size_t)kc*512);
        vac1[kc] = *(const bf16x8*)(vbase1 + (size_t)kc*512);
    }
    {
        f32x4 s[4];
        #pragma unroll
        for (int nj = 0; nj < 4; nj++) {
            f32x4 a = {0.f, 0.f, 0.f, 0.f};
            a = MFMA32(ka0, qf[nj][0], a);
            a = MFMA32(ka1, qf[nj][1], a);
            s[nj] = a;
        }
        #pragma unroll
        for (int nj = 0; nj < 4; nj++) {
            const float p0 = EXP2F(s[nj][0]*L2E);
            const float p1 = EXP2F(s[nj][1]*L2E);
            const float p2 = EXP2F(s[nj][2]*L2E);
            const float p3 = EXP2F(s[nj][3]*L2E);
            zacc[nj] += (p0 + p1) + (p2 + p3);
            uint2 u;
            u.x = pack_trunc(p0, p1);
            u.y = pack_trunc(p2, p3);
            p_l[0][Uw + nj*17] = u;
        }
    }
    ka0 = *(const bf16x8*)(kbase + 8192);        // m-tile 1
    ka1 = *(const bf16x8*)(kbase + 8192 + 512);

    int buf = 0;
    for (int mt = 0; mt < 31; mt++) {
        __syncthreads();
        // --- single merged region: QK_{mt+1} || PV_mt || exp+z_{mt+1} ---
        f32x4 s[4];
        #pragma unroll
        for (int nj = 0; nj < 4; nj++) {
            f32x4 a = {0.f, 0.f, 0.f, 0.f};
            a = MFMA32(ka0, qf[nj][0], a);
            a = MFMA32(ka1, qf[nj][1], a);
            s[nj] = a;
        }
        #pragma unroll
        for (int nj = 0; nj < 4; nj++) {
            #pragma unroll
            for (int kc = 0; kc < 4; kc++) {
                const uint2 u0 = p_l[buf][Ur0 + kc*544 + nj*17];
                const uint2 u1 = p_l[buf][Ur0 + kc*544 + nj*17 + 68];
                uint4 f = make_uint4(u0.x, u0.y, u1.x, u1.y);
                const bf16x8 pf = *(bf16x8*)&f;
                acc[0][nj] = MFMA32(vac0[kc], pf, acc[0][nj]);
                acc[1][nj] = MFMA32(vac1[kc], pf, acc[1][nj]);
            }
        }
        // prefetch: k m-tile mt+2 (clamped), v m-tile mt+1
        const int m2 = (mt < 30) ? mt + 2 : 31;
        ka0 = *(const bf16x8*)(kbase + (size_t)m2*8192);
        ka1 = *(const bf16x8*)(kbase + (size_t)m2*8192 + 512);
        bf16x8 van0[4], van1[4];
        #pragma unroll
        for (int kc = 0; kc < 4; kc++) {
            van0[kc] = *(const bf16x8*)(vbase0 + (size_t)((mt+1)*4 + kc)*512);
            van1[kc] = *(const bf16x8*)(vbase1 + (size_t)((mt+1)*4 + kc)*512);
        }

        // exp + z + write p[buf^1] for m-tile mt+1
        #pragma unroll
        for (int nj = 0; nj < 4; nj++) {
            const float p0 = EXP2F(s[nj][0]*L2E);
            const float p1 = EXP2F(s[nj][1]*L2E);
            const float p2 = EXP2F(s[nj][2]*L2E);
            const float p3 = EXP2F(s[nj][3]*L2E);
            zacc[nj] += (p0 + p1) + (p2 + p3);
            uint2 u;
            u.x = pack_trunc(p0, p1);
            u.y = pack_trunc(p2, p3);
            p_l[buf^1][Uw + nj*17] = u;
        }
        // rotate prefetch buffers (compile-time indices)
        #pragma unroll
        for (int kc = 0; kc < 4; kc++) {
            vac0[kc] = van0[kc];
            vac1[kc] = van1[kc];
        }
        buf ^= 1;
    }
    // peeled final m-tile (31): PV only
    __syncthreads();
    #pragma unroll
    for (int nj = 0; nj < 4; nj++) {
        #pragma unroll
        for (int kc = 0; kc < 4; kc++) {
            const uint2 u0 = p_l[buf][Ur0 + kc*544 + nj*17];
            const uint2 u1 = p_l[buf][Ur0 + kc*544 + nj*17 + 68];
            uint4 f = make_uint4(u0.x, u0.y, u1.x, u1.y);
            const bf16x8 pf = *(bf16x8*)&f;
            acc[0][nj] = MFMA32(vac0[kc], pf, acc[0][nj]);
            acc[1][nj] = MFMA32(vac1[kc], pf, acc[1][nj]);
        }
    }

    // z: reduce over q (lanes ^16, ^32), then over waves via LDS
    #pragma unroll
    for (int nj = 0; nj < 4; nj++) {
        zacc[nj] += __shfl_xor(zacc[nj], 16, 64);
        zacc[nj] += __shfl_xor(zacc[nj], 32, 64);
    }
    if (q == 0) {
        #pragma unroll
        for (int nj = 0; nj < 4; nj++) zl[w][16*nj + c16] = zacc[nj];
    }
    __syncthreads();

    float rz[4];
    #pragma unroll
    for (int nj = 0; nj < 4; nj++) {
        float zt = 0.f;
        #pragma unroll
        for (int w8 = 0; w8 < 8; w8++) zt += zl[w8][16*nj + c16];
        rz[nj] = 1.0f / zt;
    }

    const float g = gamma[0];
    #pragma unroll
    for (int cg = 0; cg < 2; cg++)
        #pragma unroll
        for (int nj = 0; nj < 4; nj++)
            #pragma unroll
            for (int r = 0; r < 4; r++) {
                const size_t o = ((size_t)(b*C_IN + 32*w + 16*cg + 4*q + r))*NPT
                               + n0 + 16*nj + c16;
                out[o] = g*(acc[cg][nj][r]*rz[nj]) + x[o];
            }
}

// ---------------------------------------------------------------------------
extern "C" void kernel_launch(void* const* d_in, const int* in_sizes, int n_in,
                              void* d_out, int out_size, void* d_ws, size_t ws_size,
                              hipStream_t stream)
{
    const float* x     = (const float*)d_in[0];
    const float* wq    = (const float*)d_in[1];
    const float* bq    = (const float*)d_in[2];
    const float* wk    = (const float*)d_in[3];
    const float* bk    = (const float*)d_in[4];
    const float* wv    = (const float*)d_in[5];
    const float* bv    = (const float*)d_in[6];
    const float* gamma = (const float*)d_in[7];
    float* out = (float*)d_out;

    u16* qF  = (u16*)d_ws;                              // 2 MB
    u16* kF  = qF  + (size_t)NB*NPT*CQD;                // 2 MB
    u16* vF  = kF  + (size_t)NB*NPT*CQD;                // 8 MB
    u16* wbf = vF  + (size_t)NB*C_IN*NPT;               // 192 KB
    float* bias = (float*)(wbf + 384*256);              // 384

    prep_kernel<<<dim3(386), 256, 0, stream>>>(wq, bq, wk, bk, wv, bv, wbf, bias);
    proj_kernel<<<dim3(NPT/32, NB), 256, 0, stream>>>(x, wbf, bias, qF, kF, vF);
    attn_kernel<<<dim3(256), 512, 0, stream>>>(qF, kF, vF, gamma, x, out);
}

// Round 11
// 142.571 us; speedup vs baseline: 2.1797x; 1.0148x over previous
//
#include <hip/hip_runtime.h>

#define NB   4
#define C_IN 256
#define CQD  64
#define NPT  4096
#define L2E  1.44269504088896f

typedef __attribute__((ext_vector_type(8))) short bf16x8;
typedef __attribute__((ext_vector_type(4))) float f32x4;
typedef unsigned short u16;
typedef unsigned int   u32;

#define EXP2F(x)      __builtin_amdgcn_exp2f(x)
#define MFMA32(A,B,C) __builtin_amdgcn_mfma_f32_16x16x32_bf16(A,B,C,0,0,0)

__device__ __forceinline__ u16 f2bf(float f) {          // RNE (cold paths)
    u32 u = __float_as_uint(f);
    u += 0x7fff + ((u >> 16) & 1);
    return (u16)(u >> 16);
}
// one v_perm: (bf16_trunc(hi)<<16) | bf16_trunc(lo)
__device__ __forceinline__ u32 pack_trunc(float lo, float hi) {
    return __builtin_amdgcn_perm(__float_as_uint(hi), __float_as_uint(lo), 0x07060302u);
}

// ---------------------------------------------------------------------------
// Fragment-major layouts (1 request per wave fragment load):
//   qF/kF: [b][g][half][lane][8] u16, g = seq/16, half = o-chunk/4,
//          lane = 16*q + c16 holds (row 16g+c16, o elems 8*(q+4*half)..+7).
//   vF:    [b][cg][pg][lane][8] u16, cg = c/16, pg = pos/32,
//          lane = 16*q + c16 holds (row 16cg+c16, pos elems 32pg+8q..+7).
//   wbf:   [go*8+kk][lane][8] u16, go = o/16 (0..23), kk = col-chunk/32,
//          lane = 16*q + c16 holds (row 16go+c16, cols kk*32+8q..+7).
//          Fragment stride = 512 u16 (64 lanes x 8) — R10 bug was 1024,
//          which overflowed the 98304-u16 buffer and clobbered bias.
// ---------------------------------------------------------------------------

// ---------------------------------------------------------------------------
// prep: pack wq|wk|wv into fragment-major bf16 wbf, biases into bias[384]
// ---------------------------------------------------------------------------
__global__ void prep_kernel(
    const float* __restrict__ wq, const float* __restrict__ bq,
    const float* __restrict__ wk, const float* __restrict__ bk,
    const float* __restrict__ wv, const float* __restrict__ bv,
    u16* __restrict__ wbf, float* __restrict__ bias)
{
    const int gid = blockIdx.x*256 + threadIdx.x;
    if (gid < 384*256) {
        const int r = gid >> 8, c = gid & 255;
        const float v = (r < 64) ? wq[r*256 + c]
                      : (r < 128) ? wk[(r-64)*256 + c]
                                  : wv[(r-128)*256 + c];
        // fragment-major destination (stride 512 per fragment)
        const int go  = r >> 4, c16 = r & 15;
        const int kk  = c >> 5, qh  = (c >> 3) & 3, j = c & 7;
        wbf[((size_t)(go*8 + kk))*512 + (16*qh + c16)*8 + j] = f2bf(v);
    } else if (gid < 384*256 + 384) {
        const int r = gid - 384*256;
        bias[r] = (r < 64) ? bq[r] : (r < 128) ? bk[r-64] : bv[r-128];
    }
}

// ---------------------------------------------------------------------------
// proj: MFMA pointwise projections, x read ONCE. Wave w owns tiles T=4*ot+w.
// grid (N/32, B), block 256. Epilogue stores in fragment-major layouts.
// af loads fragment-major (1 request/wave, was 16 segments).
// ---------------------------------------------------------------------------
union ProjShared {
    u16 x_t[32][264];                            // [n][c] bf16, stride 528B
    struct { u16 qk[32][136]; u16 vl[256][40]; } ep;
};

__global__ __launch_bounds__(256) void proj_kernel(
    const float* __restrict__ x, const u16* __restrict__ wbf,
    const float* __restrict__ bias,
    u16* __restrict__ qF, u16* __restrict__ kF, u16* __restrict__ vF)
{
    __shared__ ProjShared sh;

    const int t  = threadIdx.x;
    const int n0 = blockIdx.x * 32;
    const int b  = blockIdx.y;

    {   // stage x tile transposed -> bf16 LDS
        const int ln = t & 31;
        const int cg = t >> 5;
        #pragma unroll
        for (int rr = 0; rr < 8; rr++) {
            const int c = 4*cg + 32*rr;
            const float f0 = x[((size_t)(b*C_IN + c+0))*NPT + n0 + ln];
            const float f1 = x[((size_t)(b*C_IN + c+1))*NPT + n0 + ln];
            const float f2 = x[((size_t)(b*C_IN + c+2))*NPT + n0 + ln];
            const float f3 = x[((size_t)(b*C_IN + c+3))*NPT + n0 + ln];
            ushort4 u4;
            u4.x = f2bf(f0); u4.y = f2bf(f1); u4.z = f2bf(f2); u4.w = f2bf(f3);
            *(ushort4*)&sh.x_t[ln][c] = u4;
        }
    }
    __syncthreads();

    const int w = t >> 6, l = t & 63, q = l >> 4, c16 = l & 15;

    f32x4 acc[6][2];
    #pragma unroll
    for (int ot = 0; ot < 6; ot++)
        #pragma unroll
        for (int nt = 0; nt < 2; nt++)
            acc[ot][nt] = (f32x4){0.f, 0.f, 0.f, 0.f};

    #pragma unroll
    for (int kk = 0; kk < 8; kk++) {
        const bf16x8 bf0 = *(const bf16x8*)&sh.x_t[c16     ][kk*32 + 8*q];
        const bf16x8 bf1 = *(const bf16x8*)&sh.x_t[16 + c16][kk*32 + 8*q];
        #pragma unroll
        for (int ot = 0; ot < 6; ot++) {
            // fragment-major weight load: lane-contiguous (stride 512)
            const bf16x8 af = *(const bf16x8*)&wbf[((size_t)((4*ot + w)*8 + kk))*512 + l*8];
            acc[ot][0] = MFMA32(af, bf0, acc[ot][0]);
            acc[ot][1] = MFMA32(af, bf1, acc[ot][1]);
        }
    }
    __syncthreads();   // x_t dead; reuse LDS for epilogue staging

    #pragma unroll
    for (int ot = 0; ot < 6; ot++) {
        const int T  = 4*ot + w;
        const int ob = 16*T + 4*q;
        float b0 = bias[ob+0], b1 = bias[ob+1], b2 = bias[ob+2], b3 = bias[ob+3];
        #pragma unroll
        for (int nt = 0; nt < 2; nt++) {
            const f32x4 a = acc[ot][nt];
            const float v0 = a[0]+b0, v1 = a[1]+b1, v2 = a[2]+b2, v3 = a[3]+b3;
            if (ot < 2) {
                uint2 u;
                u.x = (u32)f2bf(v0) | ((u32)f2bf(v1) << 16);
                u.y = (u32)f2bf(v2) | ((u32)f2bf(v3) << 16);
                *(uint2*)&sh.ep.qk[16*nt + c16][16*T + 4*q] = u;
            } else {
                const int cb = 16*T - 128 + 4*q;
                sh.ep.vl[cb+0][16*nt + c16] = f2bf(v0);
                sh.ep.vl[cb+1][16*nt + c16] = f2bf(v1);
                sh.ep.vl[cb+2][16*nt + c16] = f2bf(v2);
                sh.ep.vl[cb+3][16*nt + c16] = f2bf(v3);
            }
        }
    }
    __syncthreads();

    {   // fragment-major global stores
        const int n    = t >> 3;
        const int c    = t & 7;
        const int g    = (n0 + n) >> 4;
        const int lane = 16*(c & 3) + (n & 15);
        const size_t dq = ((size_t)(b*256 + g))*1024 + (size_t)(c >> 2)*512 + lane*8;
        *(uint4*)&qF[dq] = *(uint4*)&sh.ep.qk[n][8*c];
        *(uint4*)&kF[dq] = *(uint4*)&sh.ep.qk[n][64 + 8*c];
        const int cg   = t >> 4, c16v = t & 15;
        const int pg   = n0 >> 5;
        u16* vdst = &vF[(((size_t)(b*16 + cg))*128 + pg)*512 + c16v*8];
        #pragma unroll
        for (int j = 0; j < 4; j++)          // lane 16j+c16v -> offset j*128
            *(uint4*)&vdst[j*128] = *(uint4*)&sh.ep.vl[t][8*j];
    }
}

// ---------------------------------------------------------------------------
// attn (FUSED softmax): block owns n-tile 64 (softmax ROW index) and
// iterates ALL m -> full denominator z[n] accumulates in-block. Unnormalized
// p~ = exp2(s*L2E); normalize once at the end: out = gamma*(acc/z) + x.
// Merged-region body [BARRIER; QK_{t+1}; PV_t; prefetch; exp+z_{t+1};
// write p[buf^1]], p dbuf, 1 barrier/iter. (unchanged from R9)
// p LDS layout (verified): unit U(w,q,nj) = (w*16+q*4+nj)*17 + c16.
// grid 256 = 4b x 64 n-tiles XCD-grouped, block 512, 1 blk/CU.
// ---------------------------------------------------------------------------
__global__ __launch_bounds__(512, 2) void attn_kernel(
    const u16* __restrict__ qF, const u16* __restrict__ kF, const u16* __restrict__ vF,
    const float* __restrict__ gamma,
    const float* __restrict__ x, float* __restrict__ out)
{
    __shared__ uint2 p_l[2][2176];   // 2 x 17408 B
    __shared__ float zl[8][68];      // per-wave z partials (padded)

    const int t = threadIdx.x;
    const int w = t >> 6, l = t & 63, q = l >> 4, c16 = l & 15;

    const int id  = blockIdx.x;
    const int xcd = id & 7;                    // dispatch round-robins XCDs
    const int jb  = id >> 3;                   // 0..31
    const int b   = xcd >> 1;                  // 2 XCDs per batch -> L2 locality
    const int ntt = ((xcd & 1) << 5) | jb;     // 32 n-tiles per XCD
    const int n0  = ntt * 64;

    // persistent q B-fragments: group gn = ntt*4 + nj (block's 64 n-rows)
    bf16x8 qf[4][2];
    #pragma unroll
    for (int nj = 0; nj < 4; nj++) {
        const u16* qp = &qF[((size_t)(b*256 + ntt*4 + nj))*1024 + l*8];
        qf[nj][0] = *(const bf16x8*)qp;
        qf[nj][1] = *(const bf16x8*)(qp + 512);
    }

    f32x4 acc[2][4];   // [cg][nj]: c = 32w + 16cg + 4q + r, n = n0 + 16nj + c16
    #pragma unroll
    for (int cg = 0; cg < 2; cg++)
        #pragma unroll
        for (int nj = 0; nj < 4; nj++)
            acc[cg][nj] = (f32x4){0.f, 0.f, 0.f, 0.f};

    float zacc[4] = {0.f, 0.f, 0.f, 0.f};   // [nj]: n = n0 + 16nj + c16 partials

    // fragment-major bases (all lane-contiguous)
    const u16* kbase  = &kF[((size_t)(b*256 + w))*1024 + l*8];        // + mt*8192
    const u16* vbase0 = &vF[(((size_t)(b*16 + 2*w))*128)*512 + l*8];  // + (mt*4+kc)*512
    const u16* vbase1 = vbase0 + (size_t)128*512;                     // cg+1

    // LDS unit indices (stride-17 units of uint2)
    const int Uw  = (w*16 + q*4)*17 + c16;                    // + nj*17
    const int Ur0 = ((q>>1)*16 + (q&1)*8)*17 + c16;           // + kc*544 + nj*17 (+68)

    // ---- prologue: m-tile 0 scores -> p[0]; stage tile-0 v, tile-1 k ----
    bf16x8 ka0 = *(const bf16x8*)kbase;
    bf16x8 ka1 = *(const bf16x8*)(kbase + 512);
    bf16x8 vac0[4], vac1[4];
    #pragma unroll
    for (int kc = 0; kc < 4; kc++) {
        vac0[kc] = *(const bf16x8*)(vbase0 + (size_t)kc*512);
        vac1[kc] = *(const bf16x8*)(vbase1 + (size_t)kc*512);
    }
    {
        f32x4 s[4];
        #pragma unroll
        for (int nj = 0; nj < 4; nj++) {
            f32x4 a = {0.f, 0.f, 0.f, 0.f};
            a = MFMA32(ka0, qf[nj][0], a);
            a = MFMA32(ka1, qf[nj][1], a);
            s[nj] = a;
        }
        #pragma unroll
        for (int nj = 0; nj < 4; nj++) {
            const float p0 = EXP2F(s[nj][0]*L2E);
            const float p1 = EXP2F(s[nj][1]*L2E);
            const float p2 = EXP2F(s[nj][2]*L2E);
            const float p3 = EXP2F(s[nj][3]*L2E);
            zacc[nj] += (p0 + p1) + (p2 + p3);
            uint2 u;
            u.x = pack_trunc(p0, p1);
            u.y = pack_trunc(p2, p3);
            p_l[0][Uw + nj*17] = u;
        }
    }
    ka0 = *(const bf16x8*)(kbase + 8192);        // m-tile 1
    ka1 = *(const bf16x8*)(kbase + 8192 + 512);

    int buf = 0;
    for (int mt = 0; mt < 31; mt++) {
        __syncthreads();
        // --- single merged region: QK_{mt+1} || PV_mt || exp+z_{mt+1} ---
        f32x4 s[4];
        #pragma unroll
        for (int nj = 0; nj < 4; nj++) {
            f32x4 a = {0.f, 0.f, 0.f, 0.f};
            a = MFMA32(ka0, qf[nj][0], a);
            a = MFMA32(ka1, qf[nj][1], a);
            s[nj] = a;
        }
        #pragma unroll
        for (int nj = 0; nj < 4; nj++) {
            #pragma unroll
            for (int kc = 0; kc < 4; kc++) {
                const uint2 u0 = p_l[buf][Ur0 + kc*544 + nj*17];
                const uint2 u1 = p_l[buf][Ur0 + kc*544 + nj*17 + 68];
                uint4 f = make_uint4(u0.x, u0.y, u1.x, u1.y);
                const bf16x8 pf = *(bf16x8*)&f;
                acc[0][nj] = MFMA32(vac0[kc], pf, acc[0][nj]);
                acc[1][nj] = MFMA32(vac1[kc], pf, acc[1][nj]);
            }
        }
        // prefetch: k m-tile mt+2 (clamped), v m-tile mt+1
        const int m2 = (mt < 30) ? mt + 2 : 31;
        ka0 = *(const bf16x8*)(kbase + (size_t)m2*8192);
        ka1 = *(const bf16x8*)(kbase + (size_t)m2*8192 + 512);
        bf16x8 van0[4], van1[4];
        #pragma unroll
        for (int kc = 0; kc < 4; kc++) {
            van0[kc] = *(const bf16x8*)(vbase0 + (size_t)((mt+1)*4 + kc)*512);
            van1[kc] = *(const bf16x8*)(vbase1 + (size_t)((mt+1)*4 + kc)*512);
        }

        // exp + z + write p[buf^1] for m-tile mt+1
        #pragma unroll
        for (int nj = 0; nj < 4; nj++) {
            const float p0 = EXP2F(s[nj][0]*L2E);
            const float p1 = EXP2F(s[nj][1]*L2E);
            const float p2 = EXP2F(s[nj][2]*L2E);
            const float p3 = EXP2F(s[nj][3]*L2E);
            zacc[nj] += (p0 + p1) + (p2 + p3);
            uint2 u;
            u.x = pack_trunc(p0, p1);
            u.y = pack_trunc(p2, p3);
            p_l[buf^1][Uw + nj*17] = u;
        }
        // rotate prefetch buffers (compile-time indices)
        #pragma unroll
        for (int kc = 0; kc < 4; kc++) {
            vac0[kc] = van0[kc];
            vac1[kc] = van1[kc];
        }
        buf ^= 1;
    }
    // peeled final m-tile (31): PV only
    __syncthreads();
    #pragma unroll
    for (int nj = 0; nj < 4; nj++) {
        #pragma unroll
        for (int kc = 0; kc < 4; kc++) {
            const uint2 u0 = p_l[buf][Ur0 + kc*544 + nj*17];
            const uint2 u1 = p_l[buf][Ur0 + kc*544 + nj*17 + 68];
            uint4 f = make_uint4(u0.x, u0.y, u1.x, u1.y);
            const bf16x8 pf = *(bf16x8*)&f;
            acc[0][nj] = MFMA32(vac0[kc], pf, acc[0][nj]);
            acc[1][nj] = MFMA32(vac1[kc], pf, acc[1][nj]);
        }
    }

    // z: reduce over q (lanes ^16, ^32), then over waves via LDS
    #pragma unroll
    for (int nj = 0; nj < 4; nj++) {
        zacc[nj] += __shfl_xor(zacc[nj], 16, 64);
        zacc[nj] += __shfl_xor(zacc[nj], 32, 64);
    }
    if (q == 0) {
        #pragma unroll
        for (int nj = 0; nj < 4; nj++) zl[w][16*nj + c16] = zacc[nj];
    }
    __syncthreads();

    float rz[4];
    #pragma unroll
    for (int nj = 0; nj < 4; nj++) {
        float zt = 0.f;
        #pragma unroll
        for (int w8 = 0; w8 < 8; w8++) zt += zl[w8][16*nj + c16];
        rz[nj] = 1.0f / zt;
    }

    const float g = gamma[0];
    #pragma unroll
    for (int cg = 0; cg < 2; cg++)
        #pragma unroll
        for (int nj = 0; nj < 4; nj++)
            #pragma unroll
            for (int r = 0; r < 4; r++) {
                const size_t o = ((size_t)(b*C_IN + 32*w + 16*cg + 4*q + r))*NPT
                               + n0 + 16*nj + c16;
                out[o] = g*(acc[cg][nj][r]*rz[nj]) + x[o];
            }
}

// ---------------------------------------------------------------------------
extern "C" void kernel_launch(void* const* d_in, const int* in_sizes, int n_in,
                              void* d_out, int out_size, void* d_ws, size_t ws_size,
                              hipStream_t stream)
{
    const float* x     = (const float*)d_in[0];
    const float* wq    = (const float*)d_in[1];
    const float* bq    = (const float*)d_in[2];
    const float* wk    = (const float*)d_in[3];
    const float* bk    = (const float*)d_in[4];
    const float* wv    = (const float*)d_in[5];
    const float* bv    = (const float*)d_in[6];
    const float* gamma = (const float*)d_in[7];
    float* out = (float*)d_out;

    u16* qF  = (u16*)d_ws;                              // 2 MB
    u16* kF  = qF  + (size_t)NB*NPT*CQD;                // 2 MB
    u16* vF  = kF  + (size_t)NB*NPT*CQD;                // 8 MB
    u16* wbf = vF  + (size_t)NB*C_IN*NPT;               // 192 KB
    float* bias = (float*)(wbf + 384*256);              // 384

    prep_kernel<<<dim3(386), 256, 0, stream>>>(wq, bq, wk, bk, wv, bv, wbf, bias);
    proj_kernel<<<dim3(NPT/32, NB), 256, 0, stream>>>(x, wbf, bias, qF, kF, vF);
    attn_kernel<<<dim3(256), 512, 0, stream>>>(qF, kF, vF, gamma, x, out);
}